// Round 11
// baseline (1432.957 us; speedup 1.0000x reference)
//
#include <hip/hip_runtime.h>
#include <math.h>

// DNC: B=32,T=64,I=64,O=64,H=512,N=128,W=64,IF=198
#define Bb 32
#define Tt 64
#define Ii 64
#define Oo 64
#define Hh 512
#define Nn 128
#define Wd 64
#define IFs 198
#define KV 640
#define G4 2048

#define NP1 128          /* 16 bb-groups x 8 jb-slices */
#define NWG 160          /* + 32 P2 wgs */
#define NT 512
#define VST2 648

// ---- LDS layout (float offsets). P1/P2 blocks overlap (roles fixed per wg).
// P2 block:
#define P2_MEM    0        /* 128*65 = 8320 */
#define P2_SCR    8320     /* 2048 */
#define P2_ITF    10368    /* 224 */
#define P2_ERASE  10592
#define P2_WVEC   10656
#define P2_USAGE  10720
#define P2_PREC   10848
#define P2_RW     10976
#define P2_WW     11104
#define P2_DOT    11232
#define P2_MN     11360
#define P2_BW     11488
#define P2_FW     11616
#define P2_SCAN   11744
#define P2_SS     11872
#define P2_SCAL   12000    /* 16 */
#define P2_BIF    12016    /* 224 */
// P1 block:
#define P1_WIF    0        /* 198*68 = 13464 (W_if slice, PADDED rows: 4-way not 32-way) */
#define P1_WOUT   13464    /* 16*580 = 9280 (W_out slice, padded) */
#define P1_BS     22744    /* 64 float4 = 256 */
#define P1_BOUT   23000    /* 16 */
#define P1_V      23016    /* 2*648 = 1296 (permuted rows) */
#define P1_CC     24312    /* 128 */
#define P1_GL     24440    /* 520 */
#define P1_HSL    24960    /* 128 */
#define P1_PACC   25088    /* 8*65 float4 = 2080 */
#define SMEM_FLOATS 27168  /* 108672 B */
#define SMEM_BYTES (SMEM_FLOATS * 4)

#define S_WWSUM 0

// WT row permutation: segment ks (160 rows) = [128 h | 16 x | 16 rvec].
__device__ __align__(16) float g_WT[KV * G4];
__device__ __align__(16) float g_bsum[G4];
typedef unsigned long long u64;
// Tagged handoffs: u64 = (step_tag << 32) | float_bits. Relaxed agent atomics,
// zero fences/flags: data self-validates, one MALL transaction per element.
__device__ u64 g_h64[2 * Bb * Hh];   // h, step-parity double buffer, tag t+1
__device__ u64 g_rv64[Bb * Wd];      // rvec(t) tag t+1
__device__ u64 g_if64[Bb * 8 * 200]; // itf partials [b][jb(8)][o pad200] tag t+1

__device__ __forceinline__ float sigf(float v) { return 1.f / (1.f + expf(-v)); }

__device__ __forceinline__ u64 ldrelax(const u64* p) {
  return __hip_atomic_load(p, __ATOMIC_RELAXED, __HIP_MEMORY_SCOPE_AGENT);
}
__device__ __forceinline__ void tstore(u64* p, unsigned tag, float v) {
  u64 val = ((u64)tag << 32) | (u64)__float_as_uint(v);
  __hip_atomic_store(p, val, __ATOMIC_RELAXED, __HIP_MEMORY_SCOPE_AGENT);
}
__device__ __forceinline__ float fixwait(const u64* p, u64 v, unsigned tag) {
  while ((unsigned)(v >> 32) != tag) {
    __builtin_amdgcn_s_sleep(1);
    v = ldrelax(p);
  }
  return __uint_as_float((unsigned)(v & 0xffffffffu));
}

#define TIN 512
__global__ __launch_bounds__(TIN) void dnc_init(const float* __restrict__ W_ih,
                                                const float* __restrict__ W_hh,
                                                const float* __restrict__ b_ih,
                                                const float* __restrict__ b_hh) {
  __shared__ float tile[64][65];
  const int tid = threadIdx.x;
  int i0 = blockIdx.x * blockDim.x + tid;
  int st = gridDim.x * blockDim.x;
  for (int idx = i0; idx < G4; idx += st) g_bsum[idx] = b_ih[idx] + b_hh[idx];
  for (int idx = i0; idx < 2 * Bb * Hh; idx += st) g_h64[idx] = 0ull;   // tag0,val0
  for (int idx = i0; idx < Bb * Wd; idx += st) g_rv64[idx] = 0ull;
  for (int idx = i0; idx < Bb * 8 * 200; idx += st) g_if64[idx] = 0ull;

  for (int tileId = blockIdx.x; tileId < 320; tileId += gridDim.x) {
    int tc = tileId >> 5, tj = tileId & 31;
    for (int k = tid; k < 64 * 64; k += TIN) {
      int r = k >> 6, cl = k & 63;
      int j = tj * 64 + r, c = tc * 64 + cl;
      tile[r][cl] = (c < 128) ? W_ih[j * 128 + c] : W_hh[j * 512 + (c - 128)];
    }
    __syncthreads();
    for (int k = tid; k < 64 * 64; k += TIN) {
      int cl = k >> 6, rjj = k & 63;
      int c = tc * 64 + cl;
      int rp;
      if (c < 64) rp = (c >> 4) * 160 + 128 + (c & 15);                 // x
      else if (c < 128) { int cc = c - 64; rp = (cc >> 4) * 160 + 144 + (cc & 15); }  // rvec
      else { int u = c - 128; rp = (u >> 7) * 160 + (u & 127); }        // h
      g_WT[(size_t)rp * G4 + tj * 64 + rjj] = tile[rjj][cl];
    }
    __syncthreads();
  }
}

__global__ __launch_bounds__(NT) void dnc_main(const float* __restrict__ x,
                                               const float* __restrict__ W_if,
                                               const float* __restrict__ b_if,
                                               const float* __restrict__ W_out,
                                               const float* __restrict__ b_out,
                                               float* __restrict__ out) {
  extern __shared__ float sm[];
  const int tid = threadIdx.x;
  const int wg = blockIdx.x;

  if (wg < NP1) {
    // ======================= P1: gates GEMV + LSTM + itf partials + out proj
    // wg = bb*8 + jb -> wg%8 == jb: each XCD's 16 P1 wgs share ONE WT slice.
    const int jb = wg & 7;
    const int bb = wg >> 3;
    const int b0 = bb * 2;
    const int o0 = (jb >> 1) * 16;     // W_out slice rows; batch = jb&1
    // preload W_if slice (padded rows: stride 68 -> 4-way conflicts, not 32-way)
    for (int i = tid; i < IFs * 64; i += NT) {
      int o = i >> 6, c = i & 63;
      sm[P1_WIF + o * 68 + c] = W_if[(size_t)o * Hh + jb * 64 + c];
    }
    // preload W_out slice (16 rows, stride 580) + b_out slice
    for (int i = tid; i < 16 * 576; i += NT) {
      int o = i / 576, c = i - o * 576;
      sm[P1_WOUT + o * 580 + c] = W_out[(size_t)(o0 + o) * 576 + c];
    }
    if (tid < 16) sm[P1_BOUT + tid] = b_out[o0 + tid];
    if (tid < 64) {
      int gq = tid >> 4, m = tid & 15;
      ((float4*)(sm + P1_BS))[tid] = ((const float4*)g_bsum)[gq * 128 + jb * 16 + m];
    }
    if (tid < 128) sm[P1_CC + tid] = 0.f;
    __syncthreads();

    for (int t = 0; t <= Tt; ++t) {
      __syncthreads();   // protect V: prior out-read complete before restaging
      {  // stage h(t-1) (tagged)
        const u64* hsrc = g_h64 + (size_t)((t + 1) & 1) * (Bb * Hh);
        const int u = tid;
        const u64* a0 = hsrc + (size_t)b0 * Hh + u;
        const u64* a1 = hsrc + (size_t)(b0 + 1) * Hh + u;
        u64 v0 = ldrelax(a0), v1 = ldrelax(a1);
        float h0 = fixwait(a0, v0, (unsigned)t);
        float h1 = fixwait(a1, v1, (unsigned)t);
        const int rp = (u >> 7) * 160 + (u & 127);
        sm[P1_V + rp] = h0;
        sm[P1_V + VST2 + rp] = h1;
        if (t < Tt && tid < 128) {  // stage x(t)
          const int bl2 = tid >> 6, i = tid & 63;
          float xv = x[((size_t)(b0 + bl2) * Tt + t) * Ii + i];
          sm[P1_V + bl2 * VST2 + (i >> 4) * 160 + 128 + (i & 15)] = xv;
        }
      }
      __syncthreads();

      {  // GEMV (t<Tt) + rvec staging (always; needed by out at t=Tt)
        const int fc = tid & 63, bl = (tid >> 6) & 1, ks = tid >> 7;
        const int lane = tid & 63;
        const int fcol = (fc >> 4) * 128 + jb * 16 + (fc & 15);
        const float* va = sm + P1_V + bl * VST2 + ks * 160;
        const float4* wp = (const float4*)g_WT + (size_t)(ks * 160) * (G4 / 4) + fcol;
        float4 a = {0.f, 0.f, 0.f, 0.f};
        if (t < Tt) {
#pragma unroll 8
          for (int r = 0; r < 144; ++r) {
            float4 w4 = wp[(size_t)r * (G4 / 4)];
            float fv = va[r];
            a.x += w4.x * fv; a.y += w4.y * fv; a.z += w4.z * fv; a.w += w4.w * fv;
          }
        }
        if (lane < 16) {  // tagged rvec(t-1): one MALL transaction, self-validating
          const u64* rp = g_rv64 + (size_t)(b0 + bl) * Wd + ks * 16 + lane;
          float rv = fixwait(rp, ldrelax(rp), (unsigned)t);
          sm[P1_V + bl * VST2 + ks * 160 + 144 + lane] = rv;
        }
        if (t < Tt) {
#pragma unroll
          for (int r = 144; r < 160; ++r) {
            float4 w4 = wp[(size_t)r * (G4 / 4)];
            float fv = va[r];
            a.x += w4.x * fv; a.y += w4.y * fv; a.z += w4.z * fv; a.w += w4.w * fv;
          }
          ((float4*)(sm + P1_PACC))[(ks * 2 + bl) * 65 + fc] = a;
        }
      }
      if (t < Tt) {
        __syncthreads();
        if (tid < 128) {  // K-reduce(4) + bias(LDS) -> GL
          const int bl = tid >> 6, fc = tid & 63;
          const float4* pa = (const float4*)(sm + P1_PACC);
          float4 g = {0.f, 0.f, 0.f, 0.f};
#pragma unroll
          for (int ks = 0; ks < 4; ++ks) {
            float4 a = pa[(ks * 2 + bl) * 65 + fc];
            g.x += a.x; g.y += a.y; g.z += a.z; g.w += a.w;
          }
          float4 bs = ((const float4*)(sm + P1_BS))[fc];
          g.x += bs.x; g.y += bs.y; g.z += bs.z; g.w += bs.w;
          const int gq = fc >> 4, m = fc & 15;
          *(float4*)(sm + P1_GL + bl * 256 + gq * 64 + m * 4) = g;
        }
        __syncthreads();
        if (tid < 128) {  // LSTM; h published tagged (no fence, no drain)
          const int bl = tid >> 6, l = tid & 63;
          const float* gl = sm + P1_GL + bl * 256;
          float ig = gl[l], fg = gl[64 + l], gg = gl[128 + l], og = gl[192 + l];
          float co = sm[P1_CC + bl * 64 + l];
          float cn = sigf(fg) * co + sigf(ig) * tanhf(gg);
          float hn = sigf(og) * tanhf(cn);
          sm[P1_CC + bl * 64 + l] = cn;
          sm[P1_HSL + bl * 64 + l] = hn;
          tstore(g_h64 + (size_t)(t & 1) * (Bb * Hh) + (size_t)(b0 + bl) * Hh + jb * 64 + l,
                 (unsigned)(t + 1), hn);
        }
        __syncthreads();
        if (tid < 2 * IFs) {  // itf partials from padded LDS W_if -> tagged stores
          const int o = tid >> 1, bl = tid & 1;
          const float4* wr = (const float4*)(sm + P1_WIF + o * 68);
          const float4* h4 = (const float4*)(sm + P1_HSL + bl * 64);
          float acc = 0.f;
#pragma unroll 8
          for (int c4 = 0; c4 < 16; ++c4) {
            float4 w = wr[c4]; float4 h = h4[c4];
            acc += w.x * h.x + w.y * h.y + w.z * h.z + w.w * h.w;
          }
          tstore(g_if64 + ((size_t)(b0 + bl) * 8 + jb) * 200 + o, (unsigned)(t + 1), acc);
        }
      }
      // ---- out(t-1) from the staged V = [x(t)|rvec(t-1)|h(t-1)] (off crit path)
      if (t > 0) {
        const int ol = tid >> 5, seg = tid & 31;
        const int blo = jb & 1;
        const float* vb = sm + P1_V + blo * VST2;
        const float* wrow = sm + P1_WOUT + ol * 580 + seg * 18;
        float p = 0.f;
#pragma unroll
        for (int q = 0; q < 18; ++q) {
          int i = seg * 18 + q;
          int rp;
          if (i < 512) rp = (i >> 7) * 160 + (i & 127);
          else { int w = i - 512; rp = (w >> 4) * 160 + 144 + (w & 15); }
          p += wrow[q] * vb[rp];
        }
        p += __shfl_down(p, 16, 32);
        p += __shfl_down(p, 8, 32);
        p += __shfl_down(p, 4, 32);
        p += __shfl_down(p, 2, 32);
        p += __shfl_down(p, 1, 32);
        if (seg == 0)
          out[((size_t)(b0 + blo) * Tt + (t - 1)) * Oo + o0 + ol] = p + sm[P1_BOUT + ol];
      }
    }
  } else {
    // ======================= P2: DNC memory for batch b (NO tail anymore)
    const int b = wg - NP1;
    float* SCR = sm + P2_SCR;
    float regL[32], regLT[32];
#pragma unroll
    for (int k = 0; k < 32; ++k) { regL[k] = 0.f; regLT[k] = 0.f; }
    for (int i = tid; i < Nn * 65; i += NT) sm[P2_MEM + i] = 0.f;
    if (tid < 128) { sm[P2_USAGE + tid] = 0.f; sm[P2_PREC + tid] = 0.f; sm[P2_RW + tid] = 0.f; }
    if (tid < IFs) sm[P2_BIF + tid] = b_if[tid];
    __syncthreads();

    for (int t = 0; t < Tt; ++t) {
      if (tid < 2 * IFs) {  // tagged itf gather: 4 loads issued, then fix-ups
        const int o = tid >> 1, hf = tid & 1;
        const u64* src = g_if64 + ((size_t)b * 8 + hf * 4) * 200 + o;
        u64 a0 = ldrelax(src), a1 = ldrelax(src + 200),
            a2 = ldrelax(src + 400), a3 = ldrelax(src + 600);
        float s = fixwait(src, a0, (unsigned)(t + 1))
                + fixwait(src + 200, a1, (unsigned)(t + 1))
                + fixwait(src + 400, a2, (unsigned)(t + 1))
                + fixwait(src + 600, a3, (unsigned)(t + 1));
        s += __shfl_xor(s, 1, 64);
        if (hf == 0) sm[P2_ITF + o] = s + sm[P2_BIF + o];
      }
      __syncthreads();
      // wave0 mega-block: scalars, ranks, scan, ww, usage
      float kn_r = 0.f, rstr_r = 0.f, rm0_r = 0.f, rm1_r = 0.f, rm2_r = 0.f;
      if (tid < 64) {
        const int li = tid, i0 = 2 * li, i1 = i0 + 1;
        float wgag = sigf(sm[P2_ITF + 128]) * sigf(sm[P2_ITF + 129]);
        float rs = sm[P2_ITF + 194];
        rstr_r = (rs > 20.f) ? rs : log1pf(expf(rs));
        float m0 = sm[P2_ITF + 195], m1 = sm[P2_ITF + 196], m2 = sm[P2_ITF + 197];
        float mx = fmaxf(m0, fmaxf(m1, m2));
        float e0 = expf(m0 - mx), e1 = expf(m1 - mx), e2 = expf(m2 - mx);
        float es = e0 + e1 + e2;
        rm0_r = e0 / es; rm1_r = e1 / es; rm2_r = e2 / es;
        float rk = sm[P2_ITF + li];
        sm[P2_ERASE + li] = sigf(rk);
        sm[P2_WVEC + li] = sm[P2_ITF + 64 + li];
        float sq = rk * rk;
#pragma unroll
        for (int off = 32; off > 0; off >>= 1) sq += __shfl_xor(sq, off, 64);
        kn_r = sqrtf(sq) + 1e-8f;
        float u0 = sm[P2_USAGE + i0], u1 = sm[P2_USAGE + i1];
        int r0 = 0, r1 = 0;
        for (int jc = 0; jc < 32; ++jc) {
          float4 uj4 = *(const float4*)(sm + P2_USAGE + jc * 4);
#pragma unroll
          for (int e = 0; e < 4; ++e) {
            float uj = (&uj4.x)[e];
            int j = jc * 4 + e;
            r0 += (uj < u0 || (uj == u0 && j < i0)) ? 1 : 0;
            r1 += (uj < u1 || (uj == u1 && j < i1)) ? 1 : 0;
          }
        }
        sm[P2_SS + r0] = u0;
        sm[P2_SS + r1] = u1;
        float s0 = sm[P2_SS + i0], s1 = sm[P2_SS + i1];
        float p = s0 * s1;
#pragma unroll
        for (int off = 1; off < 64; off <<= 1) {
          float v = __shfl_up(p, off, 64);
          if (li >= off) p *= v;
        }
        float E = __shfl_up(p, 1, 64);
        if (li == 0) E = 1.f;
        sm[P2_SCAN + i0] = E * s0;
        sm[P2_SCAN + i1] = E * s0 * s1;
        float ex0 = (r0 > 0) ? sm[P2_SCAN + r0 - 1] : 1.f;
        float ex1 = (r1 > 0) ? sm[P2_SCAN + r1 - 1] : 1.f;
        float w0 = wgag * (1.f - u0) * ex0;
        float w1 = wgag * (1.f - u1) * ex1;
        sm[P2_WW + i0] = w0; sm[P2_WW + i1] = w1;
        sm[P2_USAGE + i0] = u0 + (1.f - u0) * w0;
        sm[P2_USAGE + i1] = u1 + (1.f - u1) * w1;
        float wws = w0 + w1;
#pragma unroll
        for (int off = 32; off > 0; off >>= 1) wws += __shfl_xor(wws, off, 64);
        if (li == 0) sm[P2_SCAL + S_WWSUM] = wws;
      }
      __syncthreads();
      // pass1: fused mem+dot+mn + register link + bw/fw partials
      {
        const int n = tid & 127, ws = tid >> 7;
        float4 er[4], wv[4], kf[4];
#pragma unroll
        for (int r = 0; r < 4; ++r) {
          er[r] = *(const float4*)(sm + P2_ERASE + ws * 16 + r * 4);
          wv[r] = *(const float4*)(sm + P2_WVEC + ws * 16 + r * 4);
          kf[r] = *(const float4*)(sm + P2_ITF + ws * 16 + r * 4);
        }
        float wwn = sm[P2_WW + n];
        float dotp = 0.f, mnp = 0.f;
        const int base = P2_MEM + n * 65 + ws * 16;
#pragma unroll
        for (int q = 0; q < 16; ++q) {
          float m = sm[base + q];
          float ee = (&er[q >> 2].x)[q & 3];
          float vv = (&wv[q >> 2].x)[q & 3];
          float kk = (&kf[q >> 2].x)[q & 3];
          m = m * (1.f - wwn * ee) + wwn * vv;
          sm[base + q] = m;
          dotp += kk * m;
          mnp += m * m;
        }
        SCR[ws * 128 + n] = dotp;
        SCR[512 + ws * 128 + n] = mnp;
        const int m = n, ns = ws;
        float wwm = wwn;
        float prn = sm[P2_PREC + m];
        float bwp = 0.f, fwp = 0.f;
#pragma unroll
        for (int kq = 0; kq < 8; ++kq) {
          float4 ww4 = *(const float4*)(sm + P2_WW + ns * 32 + kq * 4);
          float4 pr4 = *(const float4*)(sm + P2_PREC + ns * 32 + kq * 4);
          float4 rw4 = *(const float4*)(sm + P2_RW + ns * 32 + kq * 4);
#pragma unroll
          for (int e = 0; e < 4; ++e) {
            int k = kq * 4 + e;
            int nn = ns * 32 + k;
            float wwo = (&ww4.x)[e];
            float pro = (&pr4.x)[e];
            float rwo = (&rw4.x)[e];
            float L = regL[k];
            L = (1.f - wwo - wwm) * L + pro * wwm;
            if (nn == m) L = 0.f;
            regL[k] = L;
            bwp += L * rwo;
            float LT = regLT[k];
            LT = (1.f - wwm - wwo) * LT + prn * wwo;
            if (nn == m) LT = 0.f;
            regLT[k] = LT;
            fwp += LT * rwo;
          }
        }
        SCR[1024 + ns * 128 + m] = bwp;
        SCR[1536 + ns * 128 + m] = fwp;
      }
      __syncthreads();
      {  // pass2: reductions + prec update
        const int n = tid & 127, role = tid >> 7;
        if (role == 0) {
          sm[P2_DOT + n] = SCR[n] + SCR[128 + n] + SCR[256 + n] + SCR[384 + n];
          float wws = sm[P2_SCAL + S_WWSUM];
          sm[P2_PREC + n] = (1.f - wws) * sm[P2_PREC + n] + sm[P2_WW + n];
        } else if (role == 1) {
          float v = SCR[512 + n] + SCR[640 + n] + SCR[768 + n] + SCR[896 + n];
          sm[P2_MN + n] = sqrtf(v) + 1e-8f;
        } else if (role == 2) {
          sm[P2_BW + n] = SCR[1024 + n] + SCR[1152 + n] + SCR[1280 + n] + SCR[1408 + n];
        } else {
          sm[P2_FW + n] = SCR[1536 + n] + SCR[1664 + n] + SCR[1792 + n] + SCR[1920 + n];
        }
      }
      __syncthreads();
      if (tid < 64) {  // cosine softmax + combine + normalize
        int i0 = 2 * tid, i1 = i0 + 1;
        float q0 = sm[P2_DOT + i0] / (kn_r * sm[P2_MN + i0]) * rstr_r;
        float q1 = sm[P2_DOT + i1] / (kn_r * sm[P2_MN + i1]) * rstr_r;
        float mx = fmaxf(q0, q1);
#pragma unroll
        for (int off = 32; off > 0; off >>= 1) mx = fmaxf(mx, __shfl_xor(mx, off, 64));
        float e0 = expf(q0 - mx), e1 = expf(q1 - mx);
        float es = e0 + e1;
#pragma unroll
        for (int off = 32; off > 0; off >>= 1) es += __shfl_xor(es, off, 64);
        float wv0 = rm0_r * sm[P2_BW + i0] + rm1_r * sm[P2_FW + i0] + rm2_r * (e0 / es) + 1e-8f;
        float wv1 = rm0_r * sm[P2_BW + i1] + rm1_r * sm[P2_FW + i1] + rm2_r * (e1 / es) + 1e-8f;
        float wsum = wv0 + wv1;
#pragma unroll
        for (int off = 32; off > 0; off >>= 1) wsum += __shfl_xor(wsum, off, 64);
        sm[P2_RW + i0] = wv0 / wsum;
        sm[P2_RW + i1] = wv1 / wsum;
      }
      __syncthreads();
      {  // rvec partials
        const int w = tid & 63, ns8 = tid >> 6;
        float4 rw4[4];
#pragma unroll
        for (int r = 0; r < 4; ++r)
          rw4[r] = *(const float4*)(sm + P2_RW + ns8 * 16 + r * 4);
        float p = 0.f;
#pragma unroll
        for (int k = 0; k < 16; ++k)
          p += (&rw4[k >> 2].x)[k & 3] * sm[P2_MEM + (ns8 * 16 + k) * 65 + w];
        SCR[ns8 * 64 + w] = p;
      }
      __syncthreads();
      if (tid < 64) {  // rvec reduce -> tagged store (critical-path exit)
        float r = 0.f;
#pragma unroll
        for (int s2 = 0; s2 < 8; ++s2) r += SCR[s2 * 64 + tid];
        tstore(g_rv64 + (size_t)b * Wd + tid, (unsigned)(t + 1), r);
      }
      __syncthreads();   // SCR protected before next pass1
    }
  }
}

extern "C" void kernel_launch(void* const* d_in, const int* in_sizes, int n_in,
                              void* d_out, int out_size, void* d_ws, size_t ws_size,
                              hipStream_t stream) {
  (void)in_sizes; (void)n_in; (void)d_ws; (void)ws_size; (void)out_size;
  const float* x    = (const float*)d_in[0];
  const float* W_ih = (const float*)d_in[1];
  const float* W_hh = (const float*)d_in[2];
  const float* b_ih = (const float*)d_in[3];
  const float* b_hh = (const float*)d_in[4];
  const float* W_if = (const float*)d_in[5];
  const float* b_if = (const float*)d_in[6];
  const float* W_out = (const float*)d_in[7];
  const float* b_out = (const float*)d_in[8];
  float* out = (float*)d_out;

  dnc_init<<<320, TIN, 0, stream>>>(W_ih, W_hh, b_ih, b_hh);

  hipFuncSetAttribute((const void*)dnc_main,
                      hipFuncAttributeMaxDynamicSharedMemorySize, SMEM_BYTES);

  void* args[] = {(void*)&x, (void*)&W_if, (void*)&b_if,
                  (void*)&W_out, (void*)&b_out, (void*)&out};
  hipLaunchCooperativeKernel((void*)dnc_main, dim3(NWG), dim3(NT), args,
                             SMEM_BYTES, stream);
}

// Round 12
// 1088.861 us; speedup vs baseline: 1.3160x; 1.3160x over previous
//
#include <hip/hip_runtime.h>
#include <math.h>

// DNC: B=32,T=64,I=64,O=64,H=512,N=128,W=64,IF=198
#define Bb 32
#define Tt 64
#define Ii 64
#define Oo 64
#define Hh 512
#define Nn 128
#define Wd 64
#define IFs 198
#define KV 640
#define G4 2048

#define NP1 128          /* 16 bb-groups x 8 jb-slices */
#define NWG 160          /* + 32 P2 wgs */
#define NT 512
#define VST2 648

// ---- LDS layout (float offsets). P1/P2 blocks overlap (roles fixed per wg).
// P2 block (identical to R10):
#define P2_MEM    0        /* 128*65 = 8320 */
#define P2_H      8320     /* 576 [h|rvec] */
#define P2_SCR    8896     /* 2048 */
#define P2_ITF    10944    /* 224 */
#define P2_ERASE  11168
#define P2_WVEC   11232
#define P2_USAGE  11296
#define P2_PREC   11424
#define P2_RW     11552
#define P2_WW     11680
#define P2_DOT    11808
#define P2_MN     11936
#define P2_BW     12064
#define P2_FW     12192
#define P2_SCAN   12320
#define P2_SS     12448
#define P2_SCAL   12576    /* 16 */
#define P2_BIF    12592    /* 224 */
// P1 block (W_if rows PADDED to 68: 4-way conflicts instead of 32-way):
#define P1_WIF    0        /* 198*68 = 13464 */
#define P1_BS     13464    /* 64 float4 = 256 */
#define P1_V      13720    /* 2*648 = 1296 (permuted rows) */
#define P1_CC     15016    /* 128 */
#define P1_GL     15144    /* 520 */
#define P1_HSL    15664    /* 128 */
#define P1_PACC   15792    /* 8*65 float4 = 2080 */
#define SMEM_FLOATS 17872  /* 71488 B */
#define SMEM_BYTES (SMEM_FLOATS * 4)

#define S_WWSUM 0

// WT row permutation: segment ks (160 rows) = [128 h | 16 x | 16 rvec].
__device__ __align__(16) float g_WT[KV * G4];
__device__ __align__(16) float g_bsum[G4];
typedef unsigned long long u64;
// Tagged handoffs: u64 = (step_tag << 32) | float_bits. Relaxed agent atomics,
// zero fences/flags: data self-validates, one MALL transaction per element.
__device__ u64 g_h64[2 * Bb * Hh];   // h, step-parity double buffer, tag t+1
__device__ u64 g_rv64[Bb * Wd];      // rvec(t) tag t+1
__device__ u64 g_if64[Bb * 8 * 200]; // itf partials [b][jb(8)][o pad200] tag t+1

__device__ __forceinline__ float sigf(float v) { return 1.f / (1.f + expf(-v)); }

__device__ __forceinline__ u64 ldrelax(const u64* p) {
  return __hip_atomic_load(p, __ATOMIC_RELAXED, __HIP_MEMORY_SCOPE_AGENT);
}
__device__ __forceinline__ void tstore(u64* p, unsigned tag, float v) {
  u64 val = ((u64)tag << 32) | (u64)__float_as_uint(v);
  __hip_atomic_store(p, val, __ATOMIC_RELAXED, __HIP_MEMORY_SCOPE_AGENT);
}
__device__ __forceinline__ float fixwait(const u64* p, u64 v, unsigned tag) {
  while ((unsigned)(v >> 32) != tag) {
    __builtin_amdgcn_s_sleep(1);
    v = ldrelax(p);
  }
  return __uint_as_float((unsigned)(v & 0xffffffffu));
}

#define TIN 512
__global__ __launch_bounds__(TIN) void dnc_init(const float* __restrict__ W_ih,
                                                const float* __restrict__ W_hh,
                                                const float* __restrict__ b_ih,
                                                const float* __restrict__ b_hh) {
  __shared__ float tile[64][65];
  const int tid = threadIdx.x;
  int i0 = blockIdx.x * blockDim.x + tid;
  int st = gridDim.x * blockDim.x;
  for (int idx = i0; idx < G4; idx += st) g_bsum[idx] = b_ih[idx] + b_hh[idx];
  for (int idx = i0; idx < 2 * Bb * Hh; idx += st) g_h64[idx] = 0ull;   // tag0,val0
  for (int idx = i0; idx < Bb * Wd; idx += st) g_rv64[idx] = 0ull;
  for (int idx = i0; idx < Bb * 8 * 200; idx += st) g_if64[idx] = 0ull;

  for (int tileId = blockIdx.x; tileId < 320; tileId += gridDim.x) {
    int tc = tileId >> 5, tj = tileId & 31;
    for (int k = tid; k < 64 * 64; k += TIN) {
      int r = k >> 6, cl = k & 63;
      int j = tj * 64 + r, c = tc * 64 + cl;
      tile[r][cl] = (c < 128) ? W_ih[j * 128 + c] : W_hh[j * 512 + (c - 128)];
    }
    __syncthreads();
    for (int k = tid; k < 64 * 64; k += TIN) {
      int cl = k >> 6, rjj = k & 63;
      int c = tc * 64 + cl;
      int rp;
      if (c < 64) rp = (c >> 4) * 160 + 128 + (c & 15);                 // x
      else if (c < 128) { int cc = c - 64; rp = (cc >> 4) * 160 + 144 + (cc & 15); }  // rvec
      else { int u = c - 128; rp = (u >> 7) * 160 + (u & 127); }        // h
      g_WT[(size_t)rp * G4 + tj * 64 + rjj] = tile[rjj][cl];
    }
    __syncthreads();
  }
}

__global__ __launch_bounds__(NT) void dnc_main(const float* __restrict__ x,
                                               const float* __restrict__ W_if,
                                               const float* __restrict__ b_if,
                                               const float* __restrict__ W_out,
                                               const float* __restrict__ b_out,
                                               float* __restrict__ out) {
  extern __shared__ float sm[];
  const int tid = threadIdx.x;
  const int wg = blockIdx.x;

  if (wg < NP1) {
    // ======================= P1: gates GEMV + LSTM + itf partials
    // wg = bb*8 + jb -> wg%8 == jb: each XCD's 16 P1 wgs share ONE WT slice.
    const int jb = wg & 7;
    const int bb = wg >> 3;
    const int b0 = bb * 2;
    // preload W_if slice with PADDED rows (stride 68)
    for (int i = tid; i < IFs * 64; i += NT) {
      int o = i >> 6, c = i & 63;
      sm[P1_WIF + o * 68 + c] = W_if[(size_t)o * Hh + jb * 64 + c];
    }
    if (tid < 64) {
      int gq = tid >> 4, m = tid & 15;
      ((float4*)(sm + P1_BS))[tid] = ((const float4*)g_bsum)[gq * 128 + jb * 16 + m];
    }
    if (tid < 128) sm[P1_CC + tid] = 0.f;
    __syncthreads();

    for (int t = 0; t < Tt; ++t) {
      {  // stage h(t-1) (tagged: data+sync in one transaction per element)
        const u64* hsrc = g_h64 + (size_t)((t + 1) & 1) * (Bb * Hh);
        const int u = tid;   // 0..511
        const u64* a0 = hsrc + (size_t)b0 * Hh + u;
        const u64* a1 = hsrc + (size_t)(b0 + 1) * Hh + u;
        u64 v0 = ldrelax(a0), v1 = ldrelax(a1);     // both issued before fixups
        float h0 = fixwait(a0, v0, (unsigned)t);
        float h1 = fixwait(a1, v1, (unsigned)t);
        const int rp = (u >> 7) * 160 + (u & 127);
        sm[P1_V + rp] = h0;
        sm[P1_V + VST2 + rp] = h1;
        if (tid < 128) {  // stage x
          const int bl2 = tid >> 6, i = tid & 63;
          float xv = x[((size_t)(b0 + bl2) * Tt + t) * Ii + i];
          sm[P1_V + bl2 * VST2 + (i >> 4) * 160 + 128 + (i & 15)] = xv;
        }
      }
      __syncthreads();

      // GEMV: wave w: bl = w&1, ks = w>>1. 144 h/x rows, then tagged rvec, 16 rows.
      {
        const int fc = tid & 63, bl = (tid >> 6) & 1, ks = tid >> 7;
        const int lane = tid & 63;
        const int fcol = (fc >> 4) * 128 + jb * 16 + (fc & 15);
        const float* va = sm + P1_V + bl * VST2 + ks * 160;
        const float4* wp = (const float4*)g_WT + (size_t)(ks * 160) * (G4 / 4) + fcol;
        float4 a = {0.f, 0.f, 0.f, 0.f};
#pragma unroll 8
        for (int r = 0; r < 144; ++r) {
          float4 w4 = wp[(size_t)r * (G4 / 4)];
          float fv = va[r];
          a.x += w4.x * fv; a.y += w4.y * fv; a.z += w4.z * fv; a.w += w4.w * fv;
        }
        if (lane < 16) {  // tagged rvec: one MALL transaction, self-validating
          const u64* rp = g_rv64 + (size_t)(b0 + bl) * Wd + ks * 16 + lane;
          float rv = fixwait(rp, ldrelax(rp), (unsigned)t);
          sm[P1_V + bl * VST2 + ks * 160 + 144 + lane] = rv;
        }
#pragma unroll
        for (int r = 144; r < 160; ++r) {
          float4 w4 = wp[(size_t)r * (G4 / 4)];
          float fv = va[r];
          a.x += w4.x * fv; a.y += w4.y * fv; a.z += w4.z * fv; a.w += w4.w * fv;
        }
        ((float4*)(sm + P1_PACC))[(ks * 2 + bl) * 65 + fc] = a;
      }
      __syncthreads();
      if (tid < 128) {  // K-reduce(4) + bias(LDS) -> GL
        const int bl = tid >> 6, fc = tid & 63;
        const float4* pa = (const float4*)(sm + P1_PACC);
        float4 g = {0.f, 0.f, 0.f, 0.f};
#pragma unroll
        for (int ks = 0; ks < 4; ++ks) {
          float4 a = pa[(ks * 2 + bl) * 65 + fc];
          g.x += a.x; g.y += a.y; g.z += a.z; g.w += a.w;
        }
        float4 bs = ((const float4*)(sm + P1_BS))[fc];
        g.x += bs.x; g.y += bs.y; g.z += bs.z; g.w += bs.w;
        const int gq = fc >> 4, m = fc & 15;
        *(float4*)(sm + P1_GL + bl * 256 + gq * 64 + m * 4) = g;
      }
      __syncthreads();
      if (tid < 128) {  // LSTM; h published as tagged u64 (no fence, no drain)
        const int bl = tid >> 6, l = tid & 63;
        const float* gl = sm + P1_GL + bl * 256;
        float ig = gl[l], fg = gl[64 + l], gg = gl[128 + l], og = gl[192 + l];
        float co = sm[P1_CC + bl * 64 + l];
        float cn = sigf(fg) * co + sigf(ig) * tanhf(gg);
        float hn = sigf(og) * tanhf(cn);
        sm[P1_CC + bl * 64 + l] = cn;
        sm[P1_HSL + bl * 64 + l] = hn;
        tstore(g_h64 + (size_t)(t & 1) * (Bb * Hh) + (size_t)(b0 + bl) * Hh + jb * 64 + l,
               (unsigned)(t + 1), hn);
      }
      __syncthreads();
      if (tid < 2 * IFs) {  // itf partials from padded LDS W_if -> tagged stores
        const int o = tid >> 1, bl = tid & 1;
        const float4* wr = (const float4*)(sm + P1_WIF + o * 68);
        const float4* h4 = (const float4*)(sm + P1_HSL + bl * 64);
        float acc = 0.f;
#pragma unroll 8
        for (int c4 = 0; c4 < 16; ++c4) {
          float4 w = wr[c4]; float4 h = h4[c4];
          acc += w.x * h.x + w.y * h.y + w.z * h.z + w.w * h.w;
        }
        tstore(g_if64 + ((size_t)(b0 + bl) * 8 + jb) * 200 + o, (unsigned)(t + 1), acc);
      }
      // next iteration's staging writes P1_V (disjoint from WIF/HSL) -> safe
    }
  } else {
    // ======================= P2: DNC memory for batch b
    const int b = wg - NP1;
    float* SCR = sm + P2_SCR;
    float regL[32], regLT[32];
#pragma unroll
    for (int k = 0; k < 32; ++k) { regL[k] = 0.f; regLT[k] = 0.f; }
    for (int i = tid; i < Nn * 65; i += NT) sm[P2_MEM + i] = 0.f;
    if (tid < 128) { sm[P2_USAGE + tid] = 0.f; sm[P2_PREC + tid] = 0.f; sm[P2_RW + tid] = 0.f; }
    if (tid < IFs) sm[P2_BIF + tid] = b_if[tid];
    __syncthreads();

    for (int t = 0; t < Tt; ++t) {
      if (tid < 2 * IFs) {  // tagged itf gather: 4 loads issued, then fix-ups
        const int o = tid >> 1, hf = tid & 1;
        const u64* src = g_if64 + ((size_t)b * 8 + hf * 4) * 200 + o;
        u64 a0 = ldrelax(src), a1 = ldrelax(src + 200),
            a2 = ldrelax(src + 400), a3 = ldrelax(src + 600);
        float s = fixwait(src, a0, (unsigned)(t + 1))
                + fixwait(src + 200, a1, (unsigned)(t + 1))
                + fixwait(src + 400, a2, (unsigned)(t + 1))
                + fixwait(src + 600, a3, (unsigned)(t + 1));
        s += __shfl_xor(s, 1, 64);
        if (hf == 0) sm[P2_ITF + o] = s + sm[P2_BIF + o];
      }
      __syncthreads();
      // wave0 mega-block: scalars, ranks, scan, ww, usage
      float kn_r = 0.f, rstr_r = 0.f, rm0_r = 0.f, rm1_r = 0.f, rm2_r = 0.f;
      if (tid < 64) {
        const int li = tid, i0 = 2 * li, i1 = i0 + 1;
        float wgag = sigf(sm[P2_ITF + 128]) * sigf(sm[P2_ITF + 129]);
        float rs = sm[P2_ITF + 194];
        rstr_r = (rs > 20.f) ? rs : log1pf(expf(rs));
        float m0 = sm[P2_ITF + 195], m1 = sm[P2_ITF + 196], m2 = sm[P2_ITF + 197];
        float mx = fmaxf(m0, fmaxf(m1, m2));
        float e0 = expf(m0 - mx), e1 = expf(m1 - mx), e2 = expf(m2 - mx);
        float es = e0 + e1 + e2;
        rm0_r = e0 / es; rm1_r = e1 / es; rm2_r = e2 / es;
        float rk = sm[P2_ITF + li];
        sm[P2_ERASE + li] = sigf(rk);
        sm[P2_WVEC + li] = sm[P2_ITF + 64 + li];
        float sq = rk * rk;
#pragma unroll
        for (int off = 32; off > 0; off >>= 1) sq += __shfl_xor(sq, off, 64);
        kn_r = sqrtf(sq) + 1e-8f;
        float u0 = sm[P2_USAGE + i0], u1 = sm[P2_USAGE + i1];
        int r0 = 0, r1 = 0;
        for (int jc = 0; jc < 32; ++jc) {
          float4 uj4 = *(const float4*)(sm + P2_USAGE + jc * 4);
#pragma unroll
          for (int e = 0; e < 4; ++e) {
            float uj = (&uj4.x)[e];
            int j = jc * 4 + e;
            r0 += (uj < u0 || (uj == u0 && j < i0)) ? 1 : 0;
            r1 += (uj < u1 || (uj == u1 && j < i1)) ? 1 : 0;
          }
        }
        sm[P2_SS + r0] = u0;
        sm[P2_SS + r1] = u1;
        float s0 = sm[P2_SS + i0], s1 = sm[P2_SS + i1];
        float p = s0 * s1;
#pragma unroll
        for (int off = 1; off < 64; off <<= 1) {
          float v = __shfl_up(p, off, 64);
          if (li >= off) p *= v;
        }
        float E = __shfl_up(p, 1, 64);
        if (li == 0) E = 1.f;
        sm[P2_SCAN + i0] = E * s0;
        sm[P2_SCAN + i1] = E * s0 * s1;
        float ex0 = (r0 > 0) ? sm[P2_SCAN + r0 - 1] : 1.f;
        float ex1 = (r1 > 0) ? sm[P2_SCAN + r1 - 1] : 1.f;
        float w0 = wgag * (1.f - u0) * ex0;
        float w1 = wgag * (1.f - u1) * ex1;
        sm[P2_WW + i0] = w0; sm[P2_WW + i1] = w1;
        sm[P2_USAGE + i0] = u0 + (1.f - u0) * w0;
        sm[P2_USAGE + i1] = u1 + (1.f - u1) * w1;
        float wws = w0 + w1;
#pragma unroll
        for (int off = 32; off > 0; off >>= 1) wws += __shfl_xor(wws, off, 64);
        if (li == 0) sm[P2_SCAL + S_WWSUM] = wws;
      }
      __syncthreads();
      // pass1: fused mem+dot+mn + register link + bw/fw partials
      {
        const int n = tid & 127, ws = tid >> 7;
        float4 er[4], wv[4], kf[4];
#pragma unroll
        for (int r = 0; r < 4; ++r) {
          er[r] = *(const float4*)(sm + P2_ERASE + ws * 16 + r * 4);
          wv[r] = *(const float4*)(sm + P2_WVEC + ws * 16 + r * 4);
          kf[r] = *(const float4*)(sm + P2_ITF + ws * 16 + r * 4);
        }
        float wwn = sm[P2_WW + n];
        float dotp = 0.f, mnp = 0.f;
        const int base = P2_MEM + n * 65 + ws * 16;
#pragma unroll
        for (int q = 0; q < 16; ++q) {
          float m = sm[base + q];
          float ee = (&er[q >> 2].x)[q & 3];
          float vv = (&wv[q >> 2].x)[q & 3];
          float kk = (&kf[q >> 2].x)[q & 3];
          m = m * (1.f - wwn * ee) + wwn * vv;
          sm[base + q] = m;
          dotp += kk * m;
          mnp += m * m;
        }
        SCR[ws * 128 + n] = dotp;
        SCR[512 + ws * 128 + n] = mnp;
        const int m = n, ns = ws;
        float wwm = wwn;
        float prn = sm[P2_PREC + m];
        float bwp = 0.f, fwp = 0.f;
#pragma unroll
        for (int kq = 0; kq < 8; ++kq) {
          float4 ww4 = *(const float4*)(sm + P2_WW + ns * 32 + kq * 4);
          float4 pr4 = *(const float4*)(sm + P2_PREC + ns * 32 + kq * 4);
          float4 rw4 = *(const float4*)(sm + P2_RW + ns * 32 + kq * 4);
#pragma unroll
          for (int e = 0; e < 4; ++e) {
            int k = kq * 4 + e;
            int nn = ns * 32 + k;
            float wwo = (&ww4.x)[e];
            float pro = (&pr4.x)[e];
            float rwo = (&rw4.x)[e];
            float L = regL[k];
            L = (1.f - wwo - wwm) * L + pro * wwm;
            if (nn == m) L = 0.f;
            regL[k] = L;
            bwp += L * rwo;
            float LT = regLT[k];
            LT = (1.f - wwm - wwo) * LT + prn * wwo;
            if (nn == m) LT = 0.f;
            regLT[k] = LT;
            fwp += LT * rwo;
          }
        }
        SCR[1024 + ns * 128 + m] = bwp;
        SCR[1536 + ns * 128 + m] = fwp;
      }
      __syncthreads();
      {  // pass2: reductions + prec update
        const int n = tid & 127, role = tid >> 7;
        if (role == 0) {
          sm[P2_DOT + n] = SCR[n] + SCR[128 + n] + SCR[256 + n] + SCR[384 + n];
          float wws = sm[P2_SCAL + S_WWSUM];
          sm[P2_PREC + n] = (1.f - wws) * sm[P2_PREC + n] + sm[P2_WW + n];
        } else if (role == 1) {
          float v = SCR[512 + n] + SCR[640 + n] + SCR[768 + n] + SCR[896 + n];
          sm[P2_MN + n] = sqrtf(v) + 1e-8f;
        } else if (role == 2) {
          sm[P2_BW + n] = SCR[1024 + n] + SCR[1152 + n] + SCR[1280 + n] + SCR[1408 + n];
        } else {
          sm[P2_FW + n] = SCR[1536 + n] + SCR[1664 + n] + SCR[1792 + n] + SCR[1920 + n];
        }
      }
      __syncthreads();
      if (tid < 64) {  // cosine softmax + combine + normalize
        int i0 = 2 * tid, i1 = i0 + 1;
        float q0 = sm[P2_DOT + i0] / (kn_r * sm[P2_MN + i0]) * rstr_r;
        float q1 = sm[P2_DOT + i1] / (kn_r * sm[P2_MN + i1]) * rstr_r;
        float mx = fmaxf(q0, q1);
#pragma unroll
        for (int off = 32; off > 0; off >>= 1) mx = fmaxf(mx, __shfl_xor(mx, off, 64));
        float e0 = expf(q0 - mx), e1 = expf(q1 - mx);
        float es = e0 + e1;
#pragma unroll
        for (int off = 32; off > 0; off >>= 1) es += __shfl_xor(es, off, 64);
        float wv0 = rm0_r * sm[P2_BW + i0] + rm1_r * sm[P2_FW + i0] + rm2_r * (e0 / es) + 1e-8f;
        float wv1 = rm0_r * sm[P2_BW + i1] + rm1_r * sm[P2_FW + i1] + rm2_r * (e1 / es) + 1e-8f;
        float wsum = wv0 + wv1;
#pragma unroll
        for (int off = 32; off > 0; off >>= 1) wsum += __shfl_xor(wsum, off, 64);
        sm[P2_RW + i0] = wv0 / wsum;
        sm[P2_RW + i1] = wv1 / wsum;
      }
      __syncthreads();
      {  // rvec partials
        const int w = tid & 63, ns8 = tid >> 6;
        float4 rw4[4];
#pragma unroll
        for (int r = 0; r < 4; ++r)
          rw4[r] = *(const float4*)(sm + P2_RW + ns8 * 16 + r * 4);
        float p = 0.f;
#pragma unroll
        for (int k = 0; k < 16; ++k)
          p += (&rw4[k >> 2].x)[k & 3] * sm[P2_MEM + (ns8 * 16 + k) * 65 + w];
        SCR[ns8 * 64 + w] = p;
      }
      __syncthreads();
      if (tid < 64) {  // rvec reduce -> tagged store (critical-path exit, no fence)
        float r = 0.f;
#pragma unroll
        for (int s2 = 0; s2 < 8; ++s2) r += SCR[s2 * 64 + tid];
        sm[P2_H + 512 + tid] = r;
        tstore(g_rv64 + (size_t)b * Wd + tid, (unsigned)(t + 1), r);
      }
      __syncthreads();
      // ---- tail (hidden behind P1's next main GEMV): tagged h gather + out proj
      if (tid < 256) {
        const u64* hsrc = g_h64 + (size_t)(t & 1) * (Bb * Hh) + (size_t)b * Hh;
        const u64* a0 = hsrc + tid * 2;
        const u64* a1 = hsrc + tid * 2 + 1;
        u64 v0 = ldrelax(a0), v1 = ldrelax(a1);
        sm[P2_H + tid * 2] = fixwait(a0, v0, (unsigned)(t + 1));
        sm[P2_H + tid * 2 + 1] = fixwait(a1, v1, (unsigned)(t + 1));
      }
      __syncthreads();
      {
        const int o = tid >> 3, seg = tid & 7;
        const float4* wrow = (const float4*)(W_out + (size_t)o * 576) + seg * 18;
        const float4* hb = (const float4*)(sm + P2_H) + seg * 18;
        float p = 0.f;
#pragma unroll
        for (int q = 0; q < 18; ++q) {
          float4 w = wrow[q]; float4 h = hb[q];
          p += w.x * h.x + w.y * h.y + w.z * h.z + w.w * h.w;
        }
        p += __shfl_down(p, 4, 8);
        p += __shfl_down(p, 2, 8);
        p += __shfl_down(p, 1, 8);
        if (seg == 0) out[((size_t)b * Tt + t) * Oo + o] = p + b_out[o];
      }
      __syncthreads();
    }
  }
}

extern "C" void kernel_launch(void* const* d_in, const int* in_sizes, int n_in,
                              void* d_out, int out_size, void* d_ws, size_t ws_size,
                              hipStream_t stream) {
  (void)in_sizes; (void)n_in; (void)d_ws; (void)ws_size; (void)out_size;
  const float* x    = (const float*)d_in[0];
  const float* W_ih = (const float*)d_in[1];
  const float* W_hh = (const float*)d_in[2];
  const float* b_ih = (const float*)d_in[3];
  const float* b_hh = (const float*)d_in[4];
  const float* W_if = (const float*)d_in[5];
  const float* b_if = (const float*)d_in[6];
  const float* W_out = (const float*)d_in[7];
  const float* b_out = (const float*)d_in[8];
  float* out = (float*)d_out;

  dnc_init<<<320, TIN, 0, stream>>>(W_ih, W_hh, b_ih, b_hh);

  hipFuncSetAttribute((const void*)dnc_main,
                      hipFuncAttributeMaxDynamicSharedMemorySize, SMEM_BYTES);

  void* args[] = {(void*)&x, (void*)&W_if, (void*)&b_if,
                  (void*)&W_out, (void*)&b_out, (void*)&out};
  hipLaunchCooperativeKernel((void*)dnc_main, dim3(NWG), dim3(NT), args,
                             SMEM_BYTES, stream);
}

// Round 13
// 881.026 us; speedup vs baseline: 1.6265x; 1.2359x over previous
//
#include <hip/hip_runtime.h>
#include <math.h>

// DNC: B=32,T=64,I=64,O=64,H=512,N=128,W=64,IF=198
#define Bb 32
#define Tt 64
#define Ii 64
#define Oo 64
#define Hh 512
#define Nn 128
#define Wd 64
#define IFs 198
#define KV 640
#define G4 2048

#define NP1 128          /* 16 bb-groups x 8 jb-slices */
#define NWG 160          /* + 32 P2 wgs */
#define NT 512
#define VST2 648

// ---- LDS layout (float offsets). P1/P2 blocks overlap (roles fixed per wg).
// P2 block:
#define P2_MEM    0        /* 128*65 = 8320 */
#define P2_H      8320     /* 576 [h|rvec] */
#define P2_SCR    8896     /* 2048 */
#define P2_ITF    10944    /* 224 */
#define P2_ERASE  11168
#define P2_WVEC   11232
#define P2_USAGE  11296
#define P2_PREC   11424
#define P2_RW     11552
#define P2_WW     11680
#define P2_DOT    11808
#define P2_MN     11936
#define P2_BW     12064
#define P2_FW     12192
#define P2_SCAN   12320
#define P2_SS     12448
#define P2_SCAL   12576    /* 16 */
#define P2_BIF    12592    /* 224 */
#define P2_ALLOC  12816    /* 128 (precomputed allocation weights) */
// P1 block (W_if rows padded to 68):
#define P1_WIF    0        /* 198*68 = 13464 */
#define P1_BS     13464    /* 64 float4 = 256 */
#define P1_V      13720    /* 2*648 = 1296 (permuted rows) */
#define P1_CC     15016    /* 128 */
#define P1_HSL    15144    /* 128 */
#define P1_PACC   15272    /* 8*65 float4 = 2080 */
#define SMEM_FLOATS 17352  /* 69408 B */
#define SMEM_BYTES (SMEM_FLOATS * 4)

#define S_WWSUM 0

// WT row permutation: segment ks (160 rows) = [128 h | 16 x | 16 rvec].
__device__ __align__(16) float g_WT[KV * G4];
__device__ __align__(16) float g_bsum[G4];
typedef unsigned long long u64;
// Tagged handoffs: u64 = (step_tag << 32) | float_bits. Relaxed agent atomics,
// zero fences/flags: data self-validates, one MALL transaction per element.
__device__ u64 g_h64[2 * Bb * Hh];   // h, step-parity double buffer, tag t+1
__device__ u64 g_rv64[Bb * Wd];      // rvec(t) tag t+1
__device__ u64 g_if64[Bb * 8 * 200]; // itf partials [b][jb(8)][o pad200] tag t+1

__device__ __forceinline__ float sigf(float v) { return 1.f / (1.f + expf(-v)); }

__device__ __forceinline__ u64 ldrelax(const u64* p) {
  return __hip_atomic_load(p, __ATOMIC_RELAXED, __HIP_MEMORY_SCOPE_AGENT);
}
__device__ __forceinline__ void tstore(u64* p, unsigned tag, float v) {
  u64 val = ((u64)tag << 32) | (u64)__float_as_uint(v);
  __hip_atomic_store(p, val, __ATOMIC_RELAXED, __HIP_MEMORY_SCOPE_AGENT);
}
__device__ __forceinline__ float fixwait(const u64* p, u64 v, unsigned tag) {
  while ((unsigned)(v >> 32) != tag) {
    __builtin_amdgcn_s_sleep(1);
    v = ldrelax(p);
  }
  return __uint_as_float((unsigned)(v & 0xffffffffu));
}

#define TIN 512
__global__ __launch_bounds__(TIN) void dnc_init(const float* __restrict__ W_ih,
                                                const float* __restrict__ W_hh,
                                                const float* __restrict__ b_ih,
                                                const float* __restrict__ b_hh) {
  __shared__ float tile[64][65];
  const int tid = threadIdx.x;
  int i0 = blockIdx.x * blockDim.x + tid;
  int st = gridDim.x * blockDim.x;
  for (int idx = i0; idx < G4; idx += st) g_bsum[idx] = b_ih[idx] + b_hh[idx];
  for (int idx = i0; idx < 2 * Bb * Hh; idx += st) g_h64[idx] = 0ull;   // tag0,val0
  for (int idx = i0; idx < Bb * Wd; idx += st) g_rv64[idx] = 0ull;
  for (int idx = i0; idx < Bb * 8 * 200; idx += st) g_if64[idx] = 0ull;

  for (int tileId = blockIdx.x; tileId < 320; tileId += gridDim.x) {
    int tc = tileId >> 5, tj = tileId & 31;
    for (int k = tid; k < 64 * 64; k += TIN) {
      int r = k >> 6, cl = k & 63;
      int j = tj * 64 + r, c = tc * 64 + cl;
      tile[r][cl] = (c < 128) ? W_ih[j * 128 + c] : W_hh[j * 512 + (c - 128)];
    }
    __syncthreads();
    for (int k = tid; k < 64 * 64; k += TIN) {
      int cl = k >> 6, rjj = k & 63;
      int c = tc * 64 + cl;
      int rp;
      if (c < 64) rp = (c >> 4) * 160 + 128 + (c & 15);                 // x
      else if (c < 128) { int cc = c - 64; rp = (cc >> 4) * 160 + 144 + (cc & 15); }  // rvec
      else { int u = c - 128; rp = (u >> 7) * 160 + (u & 127); }        // h
      g_WT[(size_t)rp * G4 + tj * 64 + rjj] = tile[rjj][cl];
    }
    __syncthreads();
  }
}

__global__ __launch_bounds__(NT) void dnc_main(const float* __restrict__ x,
                                               const float* __restrict__ W_if,
                                               const float* __restrict__ b_if,
                                               const float* __restrict__ W_out,
                                               const float* __restrict__ b_out,
                                               float* __restrict__ out) {
  extern __shared__ float sm[];
  const int tid = threadIdx.x;
  const int wg = blockIdx.x;

  if (wg < NP1) {
    // ======================= P1: gates GEMV + fused LSTM + itf partials
    // wg = bb*8 + jb -> wg%8 == jb: each XCD's 16 P1 wgs share ONE WT slice.
    const int jb = wg & 7;
    const int bb = wg >> 3;
    const int b0 = bb * 2;
    // preload W_if slice with PADDED rows (stride 68)
    for (int i = tid; i < IFs * 64; i += NT) {
      int o = i >> 6, c = i & 63;
      sm[P1_WIF + o * 68 + c] = W_if[(size_t)o * Hh + jb * 64 + c];
    }
    if (tid < 64) {
      int gq = tid >> 4, m = tid & 15;
      ((float4*)(sm + P1_BS))[tid] = ((const float4*)g_bsum)[gq * 128 + jb * 16 + m];
    }
    if (tid < 128) sm[P1_CC + tid] = 0.f;
    __syncthreads();

    for (int t = 0; t < Tt; ++t) {
      {  // stage h(t-1) (tagged: data+sync in one transaction per element)
        const u64* hsrc = g_h64 + (size_t)((t + 1) & 1) * (Bb * Hh);
        const int u = tid;   // 0..511
        const u64* a0 = hsrc + (size_t)b0 * Hh + u;
        const u64* a1 = hsrc + (size_t)(b0 + 1) * Hh + u;
        u64 v0 = ldrelax(a0), v1 = ldrelax(a1);     // both issued before fixups
        float h0 = fixwait(a0, v0, (unsigned)t);
        float h1 = fixwait(a1, v1, (unsigned)t);
        const int rp = (u >> 7) * 160 + (u & 127);
        sm[P1_V + rp] = h0;
        sm[P1_V + VST2 + rp] = h1;
        if (tid < 128) {  // stage x
          const int bl2 = tid >> 6, i = tid & 63;
          float xv = x[((size_t)(b0 + bl2) * Tt + t) * Ii + i];
          sm[P1_V + bl2 * VST2 + (i >> 4) * 160 + 128 + (i & 15)] = xv;
        }
      }
      __syncthreads();

      // GEMV: wave w: bl = w&1, ks = w>>1. 144 h/x rows, then tagged rvec, 16 rows.
      {
        const int fc = tid & 63, bl = (tid >> 6) & 1, ks = tid >> 7;
        const int lane = tid & 63;
        const int fcol = (fc >> 4) * 128 + jb * 16 + (fc & 15);
        const float* va = sm + P1_V + bl * VST2 + ks * 160;
        const float4* wp = (const float4*)g_WT + (size_t)(ks * 160) * (G4 / 4) + fcol;
        float4 a = {0.f, 0.f, 0.f, 0.f};
#pragma unroll 8
        for (int r = 0; r < 144; ++r) {
          float4 w4 = wp[(size_t)r * (G4 / 4)];
          float fv = va[r];
          a.x += w4.x * fv; a.y += w4.y * fv; a.z += w4.z * fv; a.w += w4.w * fv;
        }
        if (lane < 16) {  // tagged rvec: one MALL transaction, self-validating
          const u64* rp = g_rv64 + (size_t)(b0 + bl) * Wd + ks * 16 + lane;
          float rv = fixwait(rp, ldrelax(rp), (unsigned)t);
          sm[P1_V + bl * VST2 + ks * 160 + 144 + lane] = rv;
        }
#pragma unroll
        for (int r = 144; r < 160; ++r) {
          float4 w4 = wp[(size_t)r * (G4 / 4)];
          float fv = va[r];
          a.x += w4.x * fv; a.y += w4.y * fv; a.z += w4.z * fv; a.w += w4.w * fv;
        }
        ((float4*)(sm + P1_PACC))[(ks * 2 + bl) * 65 + fc] = a;
      }
      __syncthreads();
      if (tid < 128) {  // FUSED K-reduce + LSTM (GL round-trip + barrier removed)
        const int bl = tid >> 6, l = tid & 63;
        // PACC float idx = (ks*2+bl)*260 + gq*64 + l ; conflict-free (addr = base+l)
        const float* pb = sm + P1_PACC + bl * 260 + l;
        float gv0 = 0.f, gv1 = 0.f, gv2 = 0.f, gv3 = 0.f;
#pragma unroll
        for (int ks = 0; ks < 4; ++ks) {
          const float* pk = pb + ks * 520;
          gv0 += pk[0];
          gv1 += pk[64];
          gv2 += pk[128];
          gv3 += pk[192];
        }
        // bias float idx = gq*64 + l (same order as before: ks-sum then +bias)
        float ig = gv0 + sm[P1_BS + l];
        float fg = gv1 + sm[P1_BS + 64 + l];
        float gg = gv2 + sm[P1_BS + 128 + l];
        float og = gv3 + sm[P1_BS + 192 + l];
        float co = sm[P1_CC + bl * 64 + l];
        float cn = sigf(fg) * co + sigf(ig) * tanhf(gg);
        float hn = sigf(og) * tanhf(cn);
        sm[P1_CC + bl * 64 + l] = cn;
        sm[P1_HSL + bl * 64 + l] = hn;
        tstore(g_h64 + (size_t)(t & 1) * (Bb * Hh) + (size_t)(b0 + bl) * Hh + jb * 64 + l,
               (unsigned)(t + 1), hn);
      }
      __syncthreads();
      if (tid < 2 * IFs) {  // itf partials from padded LDS W_if -> tagged stores
        const int o = tid >> 1, bl = tid & 1;
        const float4* wr = (const float4*)(sm + P1_WIF + o * 68);
        const float4* h4 = (const float4*)(sm + P1_HSL + bl * 64);
        float acc = 0.f;
#pragma unroll 8
        for (int c4 = 0; c4 < 16; ++c4) {
          float4 w = wr[c4]; float4 h = h4[c4];
          acc += w.x * h.x + w.y * h.y + w.z * h.z + w.w * h.w;
        }
        tstore(g_if64 + ((size_t)(b0 + bl) * 8 + jb) * 200 + o, (unsigned)(t + 1), acc);
      }
      // next iteration's staging writes P1_V (disjoint from WIF/HSL) -> safe
    }
  } else {
    // ======================= P2: DNC memory for batch b
    const int b = wg - NP1;
    float* SCR = sm + P2_SCR;
    float regL[32], regLT[32];
#pragma unroll
    for (int k = 0; k < 32; ++k) { regL[k] = 0.f; regLT[k] = 0.f; }
    for (int i = tid; i < Nn * 65; i += NT) sm[P2_MEM + i] = 0.f;
    if (tid < 128) { sm[P2_USAGE + tid] = 0.f; sm[P2_PREC + tid] = 0.f; sm[P2_RW + tid] = 0.f; }
    if (tid < IFs) sm[P2_BIF + tid] = b_if[tid];
    __syncthreads();
    // prologue: alloc for t=0 from usage=0 (same code as the in-loop tail)
    if (tid < 64) {
      const int li = tid, i0 = 2 * li, i1 = i0 + 1;
      float u0 = sm[P2_USAGE + i0], u1 = sm[P2_USAGE + i1];
      int r0 = 0, r1 = 0;
      for (int jc = 0; jc < 32; ++jc) {
        float4 uj4 = *(const float4*)(sm + P2_USAGE + jc * 4);
#pragma unroll
        for (int e = 0; e < 4; ++e) {
          float uj = (&uj4.x)[e];
          int j = jc * 4 + e;
          r0 += (uj < u0 || (uj == u0 && j < i0)) ? 1 : 0;
          r1 += (uj < u1 || (uj == u1 && j < i1)) ? 1 : 0;
        }
      }
      sm[P2_SS + r0] = u0;
      sm[P2_SS + r1] = u1;
      float s0 = sm[P2_SS + i0], s1 = sm[P2_SS + i1];
      float p = s0 * s1;
#pragma unroll
      for (int off = 1; off < 64; off <<= 1) {
        float v = __shfl_up(p, off, 64);
        if (li >= off) p *= v;
      }
      float E = __shfl_up(p, 1, 64);
      if (li == 0) E = 1.f;
      sm[P2_SCAN + i0] = E * s0;
      sm[P2_SCAN + i1] = E * s0 * s1;
      float ex0 = (r0 > 0) ? sm[P2_SCAN + r0 - 1] : 1.f;
      float ex1 = (r1 > 0) ? sm[P2_SCAN + r1 - 1] : 1.f;
      sm[P2_ALLOC + i0] = (1.f - u0) * ex0;
      sm[P2_ALLOC + i1] = (1.f - u1) * ex1;
    }
    __syncthreads();

    for (int t = 0; t < Tt; ++t) {
      if (tid < 2 * IFs) {  // tagged itf gather: 4 loads issued, then fix-ups
        const int o = tid >> 1, hf = tid & 1;
        const u64* src = g_if64 + ((size_t)b * 8 + hf * 4) * 200 + o;
        u64 a0 = ldrelax(src), a1 = ldrelax(src + 200),
            a2 = ldrelax(src + 400), a3 = ldrelax(src + 600);
        float s = fixwait(src, a0, (unsigned)(t + 1))
                + fixwait(src + 200, a1, (unsigned)(t + 1))
                + fixwait(src + 400, a2, (unsigned)(t + 1))
                + fixwait(src + 600, a3, (unsigned)(t + 1));
        s += __shfl_xor(s, 1, 64);
        if (hf == 0) sm[P2_ITF + o] = s + sm[P2_BIF + o];
      }
      __syncthreads();
      // wave0 short block: scalars + ww (from precomputed alloc) + usage + wwsum
      float kn_r = 0.f, rstr_r = 0.f, rm0_r = 0.f, rm1_r = 0.f, rm2_r = 0.f;
      if (tid < 64) {
        const int li = tid, i0 = 2 * li, i1 = i0 + 1;
        float wgag = sigf(sm[P2_ITF + 128]) * sigf(sm[P2_ITF + 129]);
        float rs = sm[P2_ITF + 194];
        rstr_r = (rs > 20.f) ? rs : log1pf(expf(rs));
        float m0 = sm[P2_ITF + 195], m1 = sm[P2_ITF + 196], m2 = sm[P2_ITF + 197];
        float mx = fmaxf(m0, fmaxf(m1, m2));
        float e0 = expf(m0 - mx), e1 = expf(m1 - mx), e2 = expf(m2 - mx);
        float es = e0 + e1 + e2;
        rm0_r = e0 / es; rm1_r = e1 / es; rm2_r = e2 / es;
        float rk = sm[P2_ITF + li];
        sm[P2_ERASE + li] = sigf(rk);
        sm[P2_WVEC + li] = sm[P2_ITF + 64 + li];
        float sq = rk * rk;
#pragma unroll
        for (int off = 32; off > 0; off >>= 1) sq += __shfl_xor(sq, off, 64);
        kn_r = sqrtf(sq) + 1e-8f;
        float u0 = sm[P2_USAGE + i0], u1 = sm[P2_USAGE + i1];
        float w0 = wgag * sm[P2_ALLOC + i0];
        float w1 = wgag * sm[P2_ALLOC + i1];
        sm[P2_WW + i0] = w0; sm[P2_WW + i1] = w1;
        sm[P2_USAGE + i0] = u0 + (1.f - u0) * w0;
        sm[P2_USAGE + i1] = u1 + (1.f - u1) * w1;
        float wws = w0 + w1;
#pragma unroll
        for (int off = 32; off > 0; off >>= 1) wws += __shfl_xor(wws, off, 64);
        if (li == 0) sm[P2_SCAL + S_WWSUM] = wws;
      }
      __syncthreads();
      // pass1: fused mem+dot+mn + register link + bw/fw partials
      {
        const int n = tid & 127, ws = tid >> 7;
        float4 er[4], wv[4], kf[4];
#pragma unroll
        for (int r = 0; r < 4; ++r) {
          er[r] = *(const float4*)(sm + P2_ERASE + ws * 16 + r * 4);
          wv[r] = *(const float4*)(sm + P2_WVEC + ws * 16 + r * 4);
          kf[r] = *(const float4*)(sm + P2_ITF + ws * 16 + r * 4);
        }
        float wwn = sm[P2_WW + n];
        float dotp = 0.f, mnp = 0.f;
        const int base = P2_MEM + n * 65 + ws * 16;
#pragma unroll
        for (int q = 0; q < 16; ++q) {
          float m = sm[base + q];
          float ee = (&er[q >> 2].x)[q & 3];
          float vv = (&wv[q >> 2].x)[q & 3];
          float kk = (&kf[q >> 2].x)[q & 3];
          m = m * (1.f - wwn * ee) + wwn * vv;
          sm[base + q] = m;
          dotp += kk * m;
          mnp += m * m;
        }
        SCR[ws * 128 + n] = dotp;
        SCR[512 + ws * 128 + n] = mnp;
        const int m = n, ns = ws;
        float wwm = wwn;
        float prn = sm[P2_PREC + m];
        float bwp = 0.f, fwp = 0.f;
#pragma unroll
        for (int kq = 0; kq < 8; ++kq) {
          float4 ww4 = *(const float4*)(sm + P2_WW + ns * 32 + kq * 4);
          float4 pr4 = *(const float4*)(sm + P2_PREC + ns * 32 + kq * 4);
          float4 rw4 = *(const float4*)(sm + P2_RW + ns * 32 + kq * 4);
#pragma unroll
          for (int e = 0; e < 4; ++e) {
            int k = kq * 4 + e;
            int nn = ns * 32 + k;
            float wwo = (&ww4.x)[e];
            float pro = (&pr4.x)[e];
            float rwo = (&rw4.x)[e];
            float L = regL[k];
            L = (1.f - wwo - wwm) * L + pro * wwm;
            if (nn == m) L = 0.f;
            regL[k] = L;
            bwp += L * rwo;
            float LT = regLT[k];
            LT = (1.f - wwm - wwo) * LT + prn * wwo;
            if (nn == m) LT = 0.f;
            regLT[k] = LT;
            fwp += LT * rwo;
          }
        }
        SCR[1024 + ns * 128 + m] = bwp;
        SCR[1536 + ns * 128 + m] = fwp;
      }
      __syncthreads();
      {  // pass2: reductions + prec update
        const int n = tid & 127, role = tid >> 7;
        if (role == 0) {
          sm[P2_DOT + n] = SCR[n] + SCR[128 + n] + SCR[256 + n] + SCR[384 + n];
          float wws = sm[P2_SCAL + S_WWSUM];
          sm[P2_PREC + n] = (1.f - wws) * sm[P2_PREC + n] + sm[P2_WW + n];
        } else if (role == 1) {
          float v = SCR[512 + n] + SCR[640 + n] + SCR[768 + n] + SCR[896 + n];
          sm[P2_MN + n] = sqrtf(v) + 1e-8f;
        } else if (role == 2) {
          sm[P2_BW + n] = SCR[1024 + n] + SCR[1152 + n] + SCR[1280 + n] + SCR[1408 + n];
        } else {
          sm[P2_FW + n] = SCR[1536 + n] + SCR[1664 + n] + SCR[1792 + n] + SCR[1920 + n];
        }
      }
      __syncthreads();
      if (tid < 64) {  // cosine softmax + combine + normalize
        int i0 = 2 * tid, i1 = i0 + 1;
        float q0 = sm[P2_DOT + i0] / (kn_r * sm[P2_MN + i0]) * rstr_r;
        float q1 = sm[P2_DOT + i1] / (kn_r * sm[P2_MN + i1]) * rstr_r;
        float mx = fmaxf(q0, q1);
#pragma unroll
        for (int off = 32; off > 0; off >>= 1) mx = fmaxf(mx, __shfl_xor(mx, off, 64));
        float e0 = expf(q0 - mx), e1 = expf(q1 - mx);
        float es = e0 + e1;
#pragma unroll
        for (int off = 32; off > 0; off >>= 1) es += __shfl_xor(es, off, 64);
        float wv0 = rm0_r * sm[P2_BW + i0] + rm1_r * sm[P2_FW + i0] + rm2_r * (e0 / es) + 1e-8f;
        float wv1 = rm0_r * sm[P2_BW + i1] + rm1_r * sm[P2_FW + i1] + rm2_r * (e1 / es) + 1e-8f;
        float wsum = wv0 + wv1;
#pragma unroll
        for (int off = 32; off > 0; off >>= 1) wsum += __shfl_xor(wsum, off, 64);
        sm[P2_RW + i0] = wv0 / wsum;
        sm[P2_RW + i1] = wv1 / wsum;
      }
      __syncthreads();
      {  // rvec partials
        const int w = tid & 63, ns8 = tid >> 6;
        float4 rw4[4];
#pragma unroll
        for (int r = 0; r < 4; ++r)
          rw4[r] = *(const float4*)(sm + P2_RW + ns8 * 16 + r * 4);
        float p = 0.f;
#pragma unroll
        for (int k = 0; k < 16; ++k)
          p += (&rw4[k >> 2].x)[k & 3] * sm[P2_MEM + (ns8 * 16 + k) * 65 + w];
        SCR[ns8 * 64 + w] = p;
      }
      __syncthreads();
      if (tid < 64) {  // rvec reduce -> tagged store (critical-path exit, no fence)
        float r = 0.f;
#pragma unroll
        for (int s2 = 0; s2 < 8; ++s2) r += SCR[s2 * 64 + tid];
        sm[P2_H + 512 + tid] = r;
        tstore(g_rv64 + (size_t)b * Wd + tid, (unsigned)(t + 1), r);
      }
      __syncthreads();
      // ---- tail (hidden behind P1's next main GEMV):
      //      h gather (tid<256) + NEXT step's alloc (wave 4) in parallel
      if (tid < 256) {
        const u64* hsrc = g_h64 + (size_t)(t & 1) * (Bb * Hh) + (size_t)b * Hh;
        const u64* a0 = hsrc + tid * 2;
        const u64* a1 = hsrc + tid * 2 + 1;
        u64 v0 = ldrelax(a0), v1 = ldrelax(a1);
        sm[P2_H + tid * 2] = fixwait(a0, v0, (unsigned)(t + 1));
        sm[P2_H + tid * 2 + 1] = fixwait(a1, v1, (unsigned)(t + 1));
      } else if (tid < 320) {  // rank/sort/scan/alloc from usage(t) — off crit path
        const int li = tid & 63, i0 = 2 * li, i1 = i0 + 1;
        float u0 = sm[P2_USAGE + i0], u1 = sm[P2_USAGE + i1];
        int r0 = 0, r1 = 0;
        for (int jc = 0; jc < 32; ++jc) {
          float4 uj4 = *(const float4*)(sm + P2_USAGE + jc * 4);
#pragma unroll
          for (int e = 0; e < 4; ++e) {
            float uj = (&uj4.x)[e];
            int j = jc * 4 + e;
            r0 += (uj < u0 || (uj == u0 && j < i0)) ? 1 : 0;
            r1 += (uj < u1 || (uj == u1 && j < i1)) ? 1 : 0;
          }
        }
        sm[P2_SS + r0] = u0;
        sm[P2_SS + r1] = u1;
        float s0 = sm[P2_SS + i0], s1 = sm[P2_SS + i1];
        float p = s0 * s1;
#pragma unroll
        for (int off = 1; off < 64; off <<= 1) {
          float v = __shfl_up(p, off, 64);
          if (li >= off) p *= v;
        }
        float E = __shfl_up(p, 1, 64);
        if (li == 0) E = 1.f;
        sm[P2_SCAN + i0] = E * s0;
        sm[P2_SCAN + i1] = E * s0 * s1;
        float ex0 = (r0 > 0) ? sm[P2_SCAN + r0 - 1] : 1.f;
        float ex1 = (r1 > 0) ? sm[P2_SCAN + r1 - 1] : 1.f;
        sm[P2_ALLOC + i0] = (1.f - u0) * ex0;
        sm[P2_ALLOC + i1] = (1.f - u1) * ex1;
      }
      __syncthreads();
      {  // out projection
        const int o = tid >> 3, seg = tid & 7;
        const float4* wrow = (const float4*)(W_out + (size_t)o * 576) + seg * 18;
        const float4* hb = (const float4*)(sm + P2_H) + seg * 18;
        float p = 0.f;
#pragma unroll
        for (int q = 0; q < 18; ++q) {
          float4 w = wrow[q]; float4 h = hb[q];
          p += w.x * h.x + w.y * h.y + w.z * h.z + w.w * h.w;
        }
        p += __shfl_down(p, 4, 8);
        p += __shfl_down(p, 2, 8);
        p += __shfl_down(p, 1, 8);
        if (seg == 0) out[((size_t)b * Tt + t) * Oo + o] = p + b_out[o];
      }
      __syncthreads();
    }
  }
}

extern "C" void kernel_launch(void* const* d_in, const int* in_sizes, int n_in,
                              void* d_out, int out_size, void* d_ws, size_t ws_size,
                              hipStream_t stream) {
  (void)in_sizes; (void)n_in; (void)d_ws; (void)ws_size; (void)out_size;
  const float* x    = (const float*)d_in[0];
  const float* W_ih = (const float*)d_in[1];
  const float* W_hh = (const float*)d_in[2];
  const float* b_ih = (const float*)d_in[3];
  const float* b_hh = (const float*)d_in[4];
  const float* W_if = (const float*)d_in[5];
  const float* b_if = (const float*)d_in[6];
  const float* W_out = (const float*)d_in[7];
  const float* b_out = (const float*)d_in[8];
  float* out = (float*)d_out;

  dnc_init<<<320, TIN, 0, stream>>>(W_ih, W_hh, b_ih, b_hh);

  hipFuncSetAttribute((const void*)dnc_main,
                      hipFuncAttributeMaxDynamicSharedMemorySize, SMEM_BYTES);

  void* args[] = {(void*)&x, (void*)&W_if, (void*)&b_if,
                  (void*)&W_out, (void*)&b_out, (void*)&out};
  hipLaunchCooperativeKernel((void*)dnc_main, dim3(NWG), dim3(NT), args,
                             SMEM_BYTES, stream);
}

// Round 14
// 876.969 us; speedup vs baseline: 1.6340x; 1.0046x over previous
//
#include <hip/hip_runtime.h>
#include <math.h>

// DNC: B=32,T=64,I=64,O=64,H=512,N=128,W=64,IF=198
#define Bb 32
#define Tt 64
#define Ii 64
#define Oo 64
#define Hh 512
#define Nn 128
#define Wd 64
#define IFs 198
#define KV 640
#define G4 2048

#define NP1 128          /* 16 bb-groups x 8 jb-slices */
#define NWG 160          /* + 32 P2 wgs */
#define NT 512
#define VST2 648

// ---- LDS layout (float offsets). P1/P2 blocks overlap (roles fixed per wg).
// P2 block:
#define P2_MEM    0        /* 128*65 = 8320 */
#define P2_H      8320     /* 576 [h|rvec] */
#define P2_SCR    8896     /* 2048 */
#define P2_ITF    10944    /* 224 */
#define P2_ERASE  11168
#define P2_WVEC   11232
#define P2_USAGE  11296
#define P2_PREC   11424
#define P2_RW     11552
#define P2_WW     11680
#define P2_SCAN   11808
#define P2_SS     11936
#define P2_SCAL   12064    /* 16 */
#define P2_BIF    12080    /* 224 */
#define P2_ALLOC  12304    /* 128 (precomputed allocation weights) */
// P1 block (W_if rows padded to 68):
#define P1_WIF    0        /* 198*68 = 13464 */
#define P1_BS     13464    /* 64 float4 = 256 */
#define P1_V      13720    /* 2*648 = 1296 (permuted rows) */
#define P1_CC     15016    /* 128 */
#define P1_HSL    15144    /* 128 */
#define P1_PACC   15272    /* 8*65 float4 = 2080 */
#define SMEM_FLOATS 17352  /* 69408 B */
#define SMEM_BYTES (SMEM_FLOATS * 4)

#define S_WWSUM 0

// WT row permutation: segment ks (160 rows) = [128 h | 16 x | 16 rvec].
__device__ __align__(16) float g_WT[KV * G4];
__device__ __align__(16) float g_bsum[G4];
typedef unsigned long long u64;
// Tagged handoffs: u64 = (step_tag << 32) | float_bits. Relaxed agent atomics,
// zero fences/flags: data self-validates, one MALL transaction per element.
__device__ u64 g_h64[2 * Bb * Hh];   // h, step-parity double buffer, tag t+1
__device__ u64 g_rv64[Bb * Wd];      // rvec(t) tag t+1
__device__ u64 g_if64[Bb * 8 * 200]; // itf partials [b][jb(8)][o pad200] tag t+1

__device__ __forceinline__ float sigf(float v) { return 1.f / (1.f + expf(-v)); }

__device__ __forceinline__ u64 ldrelax(const u64* p) {
  return __hip_atomic_load(p, __ATOMIC_RELAXED, __HIP_MEMORY_SCOPE_AGENT);
}
__device__ __forceinline__ void tstore(u64* p, unsigned tag, float v) {
  u64 val = ((u64)tag << 32) | (u64)__float_as_uint(v);
  __hip_atomic_store(p, val, __ATOMIC_RELAXED, __HIP_MEMORY_SCOPE_AGENT);
}
__device__ __forceinline__ float fixwait(const u64* p, u64 v, unsigned tag) {
  while ((unsigned)(v >> 32) != tag) {
    __builtin_amdgcn_s_sleep(1);
    v = ldrelax(p);
  }
  return __uint_as_float((unsigned)(v & 0xffffffffu));
}

#define TIN 512
__global__ __launch_bounds__(TIN) void dnc_init(const float* __restrict__ W_ih,
                                                const float* __restrict__ W_hh,
                                                const float* __restrict__ b_ih,
                                                const float* __restrict__ b_hh) {
  __shared__ float tile[64][65];
  const int tid = threadIdx.x;
  int i0 = blockIdx.x * blockDim.x + tid;
  int st = gridDim.x * blockDim.x;
  for (int idx = i0; idx < G4; idx += st) g_bsum[idx] = b_ih[idx] + b_hh[idx];
  for (int idx = i0; idx < 2 * Bb * Hh; idx += st) g_h64[idx] = 0ull;   // tag0,val0
  for (int idx = i0; idx < Bb * Wd; idx += st) g_rv64[idx] = 0ull;
  for (int idx = i0; idx < Bb * 8 * 200; idx += st) g_if64[idx] = 0ull;

  for (int tileId = blockIdx.x; tileId < 320; tileId += gridDim.x) {
    int tc = tileId >> 5, tj = tileId & 31;
    for (int k = tid; k < 64 * 64; k += TIN) {
      int r = k >> 6, cl = k & 63;
      int j = tj * 64 + r, c = tc * 64 + cl;
      tile[r][cl] = (c < 128) ? W_ih[j * 128 + c] : W_hh[j * 512 + (c - 128)];
    }
    __syncthreads();
    for (int k = tid; k < 64 * 64; k += TIN) {
      int cl = k >> 6, rjj = k & 63;
      int c = tc * 64 + cl;
      int rp;
      if (c < 64) rp = (c >> 4) * 160 + 128 + (c & 15);                 // x
      else if (c < 128) { int cc = c - 64; rp = (cc >> 4) * 160 + 144 + (cc & 15); }  // rvec
      else { int u = c - 128; rp = (u >> 7) * 160 + (u & 127); }        // h
      g_WT[(size_t)rp * G4 + tj * 64 + rjj] = tile[rjj][cl];
    }
    __syncthreads();
  }
}

__global__ __launch_bounds__(NT) void dnc_main(const float* __restrict__ x,
                                               const float* __restrict__ W_if,
                                               const float* __restrict__ b_if,
                                               const float* __restrict__ W_out,
                                               const float* __restrict__ b_out,
                                               float* __restrict__ out) {
  extern __shared__ float sm[];
  const int tid = threadIdx.x;
  const int wg = blockIdx.x;

  if (wg < NP1) {
    // ======================= P1: gates GEMV + fused LSTM + itf partials
    // (unchanged from R13 — P1 is on the critical chain; touch nothing)
    const int jb = wg & 7;
    const int bb = wg >> 3;
    const int b0 = bb * 2;
    for (int i = tid; i < IFs * 64; i += NT) {
      int o = i >> 6, c = i & 63;
      sm[P1_WIF + o * 68 + c] = W_if[(size_t)o * Hh + jb * 64 + c];
    }
    if (tid < 64) {
      int gq = tid >> 4, m = tid & 15;
      ((float4*)(sm + P1_BS))[tid] = ((const float4*)g_bsum)[gq * 128 + jb * 16 + m];
    }
    if (tid < 128) sm[P1_CC + tid] = 0.f;
    __syncthreads();

    for (int t = 0; t < Tt; ++t) {
      {  // stage h(t-1) (tagged: data+sync in one transaction per element)
        const u64* hsrc = g_h64 + (size_t)((t + 1) & 1) * (Bb * Hh);
        const int u = tid;
        const u64* a0 = hsrc + (size_t)b0 * Hh + u;
        const u64* a1 = hsrc + (size_t)(b0 + 1) * Hh + u;
        u64 v0 = ldrelax(a0), v1 = ldrelax(a1);
        float h0 = fixwait(a0, v0, (unsigned)t);
        float h1 = fixwait(a1, v1, (unsigned)t);
        const int rp = (u >> 7) * 160 + (u & 127);
        sm[P1_V + rp] = h0;
        sm[P1_V + VST2 + rp] = h1;
        if (tid < 128) {
          const int bl2 = tid >> 6, i = tid & 63;
          float xv = x[((size_t)(b0 + bl2) * Tt + t) * Ii + i];
          sm[P1_V + bl2 * VST2 + (i >> 4) * 160 + 128 + (i & 15)] = xv;
        }
      }
      __syncthreads();

      {  // GEMV: 144 h/x rows, then tagged rvec, 16 rows
        const int fc = tid & 63, bl = (tid >> 6) & 1, ks = tid >> 7;
        const int lane = tid & 63;
        const int fcol = (fc >> 4) * 128 + jb * 16 + (fc & 15);
        const float* va = sm + P1_V + bl * VST2 + ks * 160;
        const float4* wp = (const float4*)g_WT + (size_t)(ks * 160) * (G4 / 4) + fcol;
        float4 a = {0.f, 0.f, 0.f, 0.f};
#pragma unroll 8
        for (int r = 0; r < 144; ++r) {
          float4 w4 = wp[(size_t)r * (G4 / 4)];
          float fv = va[r];
          a.x += w4.x * fv; a.y += w4.y * fv; a.z += w4.z * fv; a.w += w4.w * fv;
        }
        if (lane < 16) {
          const u64* rp = g_rv64 + (size_t)(b0 + bl) * Wd + ks * 16 + lane;
          float rv = fixwait(rp, ldrelax(rp), (unsigned)t);
          sm[P1_V + bl * VST2 + ks * 160 + 144 + lane] = rv;
        }
#pragma unroll
        for (int r = 144; r < 160; ++r) {
          float4 w4 = wp[(size_t)r * (G4 / 4)];
          float fv = va[r];
          a.x += w4.x * fv; a.y += w4.y * fv; a.z += w4.z * fv; a.w += w4.w * fv;
        }
        ((float4*)(sm + P1_PACC))[(ks * 2 + bl) * 65 + fc] = a;
      }
      __syncthreads();
      if (tid < 128) {  // fused K-reduce + LSTM; h published tagged
        const int bl = tid >> 6, l = tid & 63;
        const float* pb = sm + P1_PACC + bl * 260 + l;
        float gv0 = 0.f, gv1 = 0.f, gv2 = 0.f, gv3 = 0.f;
#pragma unroll
        for (int ks = 0; ks < 4; ++ks) {
          const float* pk = pb + ks * 520;
          gv0 += pk[0];
          gv1 += pk[64];
          gv2 += pk[128];
          gv3 += pk[192];
        }
        float ig = gv0 + sm[P1_BS + l];
        float fg = gv1 + sm[P1_BS + 64 + l];
        float gg = gv2 + sm[P1_BS + 128 + l];
        float og = gv3 + sm[P1_BS + 192 + l];
        float co = sm[P1_CC + bl * 64 + l];
        float cn = sigf(fg) * co + sigf(ig) * tanhf(gg);
        float hn = sigf(og) * tanhf(cn);
        sm[P1_CC + bl * 64 + l] = cn;
        sm[P1_HSL + bl * 64 + l] = hn;
        tstore(g_h64 + (size_t)(t & 1) * (Bb * Hh) + (size_t)(b0 + bl) * Hh + jb * 64 + l,
               (unsigned)(t + 1), hn);
      }
      __syncthreads();
      if (tid < 2 * IFs) {  // itf partials from padded LDS W_if -> tagged stores
        const int o = tid >> 1, bl = tid & 1;
        const float4* wr = (const float4*)(sm + P1_WIF + o * 68);
        const float4* h4 = (const float4*)(sm + P1_HSL + bl * 64);
        float acc = 0.f;
#pragma unroll 8
        for (int c4 = 0; c4 < 16; ++c4) {
          float4 w = wr[c4]; float4 h = h4[c4];
          acc += w.x * h.x + w.y * h.y + w.z * h.z + w.w * h.w;
        }
        tstore(g_if64 + ((size_t)(b0 + bl) * 8 + jb) * 200 + o, (unsigned)(t + 1), acc);
      }
    }
  } else {
    // ======================= P2: DNC memory for batch b — 6-barrier structure
    const int b = wg - NP1;
    float* SCR = sm + P2_SCR;
    float regL[32], regLT[32];
#pragma unroll
    for (int k = 0; k < 32; ++k) { regL[k] = 0.f; regLT[k] = 0.f; }
    for (int i = tid; i < Nn * 65; i += NT) sm[P2_MEM + i] = 0.f;
    if (tid < 128) { sm[P2_USAGE + tid] = 0.f; sm[P2_PREC + tid] = 0.f; sm[P2_RW + tid] = 0.f; }
    if (tid < IFs) sm[P2_BIF + tid] = b_if[tid];
    __syncthreads();
    // prologue: alloc for t=0 from usage=0
    if (tid < 64) {
      const int li = tid, i0 = 2 * li, i1 = i0 + 1;
      float u0 = sm[P2_USAGE + i0], u1 = sm[P2_USAGE + i1];
      int r0 = 0, r1 = 0;
      for (int jc = 0; jc < 32; ++jc) {
        float4 uj4 = *(const float4*)(sm + P2_USAGE + jc * 4);
#pragma unroll
        for (int e = 0; e < 4; ++e) {
          float uj = (&uj4.x)[e];
          int j = jc * 4 + e;
          r0 += (uj < u0 || (uj == u0 && j < i0)) ? 1 : 0;
          r1 += (uj < u1 || (uj == u1 && j < i1)) ? 1 : 0;
        }
      }
      sm[P2_SS + r0] = u0;
      sm[P2_SS + r1] = u1;
      float s0 = sm[P2_SS + i0], s1 = sm[P2_SS + i1];
      float p = s0 * s1;
#pragma unroll
      for (int off = 1; off < 64; off <<= 1) {
        float v = __shfl_up(p, off, 64);
        if (li >= off) p *= v;
      }
      float E = __shfl_up(p, 1, 64);
      if (li == 0) E = 1.f;
      sm[P2_SCAN + i0] = E * s0;
      sm[P2_SCAN + i1] = E * s0 * s1;
      float ex0 = (r0 > 0) ? sm[P2_SCAN + r0 - 1] : 1.f;
      float ex1 = (r1 > 0) ? sm[P2_SCAN + r1 - 1] : 1.f;
      sm[P2_ALLOC + i0] = (1.f - u0) * ex0;
      sm[P2_ALLOC + i1] = (1.f - u1) * ex1;
    }
    __syncthreads();

    for (int t = 0; t < Tt; ++t) {
      // ---- phase 1: tagged itf gather
      if (tid < 2 * IFs) {
        const int o = tid >> 1, hf = tid & 1;
        const u64* src = g_if64 + ((size_t)b * 8 + hf * 4) * 200 + o;
        u64 a0 = ldrelax(src), a1 = ldrelax(src + 200),
            a2 = ldrelax(src + 400), a3 = ldrelax(src + 600);
        float s = fixwait(src, a0, (unsigned)(t + 1))
                + fixwait(src + 200, a1, (unsigned)(t + 1))
                + fixwait(src + 400, a2, (unsigned)(t + 1))
                + fixwait(src + 600, a3, (unsigned)(t + 1));
        s += __shfl_xor(s, 1, 64);
        if (hf == 0) sm[P2_ITF + o] = s + sm[P2_BIF + o];
      }
      __syncthreads();
      // ---- phase 2: wave0 short block (scalars + ww from ALLOC + usage + wwsum)
      float kn_r = 0.f, rstr_r = 0.f, rm0_r = 0.f, rm1_r = 0.f, rm2_r = 0.f;
      if (tid < 64) {
        const int li = tid, i0 = 2 * li, i1 = i0 + 1;
        float wgag = sigf(sm[P2_ITF + 128]) * sigf(sm[P2_ITF + 129]);
        float rs = sm[P2_ITF + 194];
        rstr_r = (rs > 20.f) ? rs : log1pf(expf(rs));
        float m0 = sm[P2_ITF + 195], m1 = sm[P2_ITF + 196], m2 = sm[P2_ITF + 197];
        float mx = fmaxf(m0, fmaxf(m1, m2));
        float e0 = expf(m0 - mx), e1 = expf(m1 - mx), e2 = expf(m2 - mx);
        float es = e0 + e1 + e2;
        rm0_r = e0 / es; rm1_r = e1 / es; rm2_r = e2 / es;
        float rk = sm[P2_ITF + li];
        sm[P2_ERASE + li] = sigf(rk);
        sm[P2_WVEC + li] = sm[P2_ITF + 64 + li];
        float sq = rk * rk;
#pragma unroll
        for (int off = 32; off > 0; off >>= 1) sq += __shfl_xor(sq, off, 64);
        kn_r = sqrtf(sq) + 1e-8f;
        float u0 = sm[P2_USAGE + i0], u1 = sm[P2_USAGE + i1];
        float w0 = wgag * sm[P2_ALLOC + i0];
        float w1 = wgag * sm[P2_ALLOC + i1];
        sm[P2_WW + i0] = w0; sm[P2_WW + i1] = w1;
        sm[P2_USAGE + i0] = u0 + (1.f - u0) * w0;
        sm[P2_USAGE + i1] = u1 + (1.f - u1) * w1;
        float wws = w0 + w1;
#pragma unroll
        for (int off = 32; off > 0; off >>= 1) wws += __shfl_xor(wws, off, 64);
        if (li == 0) sm[P2_SCAL + S_WWSUM] = wws;
      }
      __syncthreads();
      // ---- phase 3: pass1 (fused mem+dot+mn + register link + bw/fw partials)
      {
        const int n = tid & 127, ws = tid >> 7;
        float4 er[4], wv[4], kf[4];
#pragma unroll
        for (int r = 0; r < 4; ++r) {
          er[r] = *(const float4*)(sm + P2_ERASE + ws * 16 + r * 4);
          wv[r] = *(const float4*)(sm + P2_WVEC + ws * 16 + r * 4);
          kf[r] = *(const float4*)(sm + P2_ITF + ws * 16 + r * 4);
        }
        float wwn = sm[P2_WW + n];
        float dotp = 0.f, mnp = 0.f;
        const int base = P2_MEM + n * 65 + ws * 16;
#pragma unroll
        for (int q = 0; q < 16; ++q) {
          float m = sm[base + q];
          float ee = (&er[q >> 2].x)[q & 3];
          float vv = (&wv[q >> 2].x)[q & 3];
          float kk = (&kf[q >> 2].x)[q & 3];
          m = m * (1.f - wwn * ee) + wwn * vv;
          sm[base + q] = m;
          dotp += kk * m;
          mnp += m * m;
        }
        SCR[ws * 128 + n] = dotp;
        SCR[512 + ws * 128 + n] = mnp;
        const int m = n, ns = ws;
        float wwm = wwn;
        float prn = sm[P2_PREC + m];
        float bwp = 0.f, fwp = 0.f;
#pragma unroll
        for (int kq = 0; kq < 8; ++kq) {
          float4 ww4 = *(const float4*)(sm + P2_WW + ns * 32 + kq * 4);
          float4 pr4 = *(const float4*)(sm + P2_PREC + ns * 32 + kq * 4);
          float4 rw4 = *(const float4*)(sm + P2_RW + ns * 32 + kq * 4);
#pragma unroll
          for (int e = 0; e < 4; ++e) {
            int k = kq * 4 + e;
            int nn = ns * 32 + k;
            float wwo = (&ww4.x)[e];
            float pro = (&pr4.x)[e];
            float rwo = (&rw4.x)[e];
            float L = regL[k];
            L = (1.f - wwo - wwm) * L + pro * wwm;
            if (nn == m) L = 0.f;
            regL[k] = L;
            bwp += L * rwo;
            float LT = regLT[k];
            LT = (1.f - wwm - wwo) * LT + prn * wwo;
            if (nn == m) LT = 0.f;
            regLT[k] = LT;
            fwp += LT * rwo;
          }
        }
        SCR[1024 + ns * 128 + m] = bwp;
        SCR[1536 + ns * 128 + m] = fwp;
      }
      __syncthreads();
      // ---- phase 4: softmax + combine + normalize (pass2 FUSED: read partials)
      if (tid < 64) {
        int i0 = 2 * tid, i1 = i0 + 1;
        float d0 = SCR[i0] + SCR[128 + i0] + SCR[256 + i0] + SCR[384 + i0];
        float d1 = SCR[i1] + SCR[128 + i1] + SCR[256 + i1] + SCR[384 + i1];
        float mn0 = sqrtf(SCR[512 + i0] + SCR[640 + i0] + SCR[768 + i0] + SCR[896 + i0]) + 1e-8f;
        float mn1 = sqrtf(SCR[512 + i1] + SCR[640 + i1] + SCR[768 + i1] + SCR[896 + i1]) + 1e-8f;
        float bw0 = SCR[1024 + i0] + SCR[1152 + i0] + SCR[1280 + i0] + SCR[1408 + i0];
        float bw1 = SCR[1024 + i1] + SCR[1152 + i1] + SCR[1280 + i1] + SCR[1408 + i1];
        float fw0 = SCR[1536 + i0] + SCR[1664 + i0] + SCR[1792 + i0] + SCR[1920 + i0];
        float fw1 = SCR[1536 + i1] + SCR[1664 + i1] + SCR[1792 + i1] + SCR[1920 + i1];
        float q0 = d0 / (kn_r * mn0) * rstr_r;
        float q1 = d1 / (kn_r * mn1) * rstr_r;
        float mx = fmaxf(q0, q1);
#pragma unroll
        for (int off = 32; off > 0; off >>= 1) mx = fmaxf(mx, __shfl_xor(mx, off, 64));
        float e0 = expf(q0 - mx), e1 = expf(q1 - mx);
        float es = e0 + e1;
#pragma unroll
        for (int off = 32; off > 0; off >>= 1) es += __shfl_xor(es, off, 64);
        float wv0 = rm0_r * bw0 + rm1_r * fw0 + rm2_r * (e0 / es) + 1e-8f;
        float wv1 = rm0_r * bw1 + rm1_r * fw1 + rm2_r * (e1 / es) + 1e-8f;
        float wsum = wv0 + wv1;
#pragma unroll
        for (int off = 32; off > 0; off >>= 1) wsum += __shfl_xor(wsum, off, 64);
        sm[P2_RW + i0] = wv0 / wsum;
        sm[P2_RW + i1] = wv1 / wsum;
      }
      __syncthreads();
      // ---- phase 5: rvec partials
      {
        const int w = tid & 63, ns8 = tid >> 6;
        float4 rw4[4];
#pragma unroll
        for (int r = 0; r < 4; ++r)
          rw4[r] = *(const float4*)(sm + P2_RW + ns8 * 16 + r * 4);
        float p = 0.f;
#pragma unroll
        for (int k = 0; k < 16; ++k)
          p += (&rw4[k >> 2].x)[k & 3] * sm[P2_MEM + (ns8 * 16 + k) * 65 + w];
        SCR[ns8 * 64 + w] = p;
      }
      __syncthreads();
      // ---- phase 6 (merged): rvec reduce+publish | h gather | alloc | prec
      if (tid < 64) {          // rvec reduce -> tagged store (critical-path exit)
        float r = 0.f;
#pragma unroll
        for (int s2 = 0; s2 < 8; ++s2) r += SCR[s2 * 64 + tid];
        sm[P2_H + 512 + tid] = r;
        tstore(g_rv64 + (size_t)b * Wd + tid, (unsigned)(t + 1), r);
      } else if (tid < 320) {  // tagged h gather (hidden behind P1's next leg)
        const int idx = tid - 64;
        const u64* hsrc = g_h64 + (size_t)(t & 1) * (Bb * Hh) + (size_t)b * Hh;
        const u64* a0 = hsrc + idx * 2;
        const u64* a1 = hsrc + idx * 2 + 1;
        u64 v0 = ldrelax(a0), v1 = ldrelax(a1);
        sm[P2_H + idx * 2] = fixwait(a0, v0, (unsigned)(t + 1));
        sm[P2_H + idx * 2 + 1] = fixwait(a1, v1, (unsigned)(t + 1));
      } else if (tid < 384) {  // next step's alloc from usage(t) (wave 5)
        const int li = tid - 320, i0 = 2 * li, i1 = i0 + 1;
        float u0 = sm[P2_USAGE + i0], u1 = sm[P2_USAGE + i1];
        int r0 = 0, r1 = 0;
        for (int jc = 0; jc < 32; ++jc) {
          float4 uj4 = *(const float4*)(sm + P2_USAGE + jc * 4);
#pragma unroll
          for (int e = 0; e < 4; ++e) {
            float uj = (&uj4.x)[e];
            int j = jc * 4 + e;
            r0 += (uj < u0 || (uj == u0 && j < i0)) ? 1 : 0;
            r1 += (uj < u1 || (uj == u1 && j < i1)) ? 1 : 0;
          }
        }
        sm[P2_SS + r0] = u0;
        sm[P2_SS + r1] = u1;
        float s0 = sm[P2_SS + i0], s1 = sm[P2_SS + i1];
        float p = s0 * s1;
#pragma unroll
        for (int off = 1; off < 64; off <<= 1) {
          float v = __shfl_up(p, off, 64);
          if (li >= off) p *= v;
        }
        float E = __shfl_up(p, 1, 64);
        if (li == 0) E = 1.f;
        sm[P2_SCAN + i0] = E * s0;
        sm[P2_SCAN + i1] = E * s0 * s1;
        float ex0 = (r0 > 0) ? sm[P2_SCAN + r0 - 1] : 1.f;
        float ex1 = (r1 > 0) ? sm[P2_SCAN + r1 - 1] : 1.f;
        sm[P2_ALLOC + i0] = (1.f - u0) * ex0;
        sm[P2_ALLOC + i1] = (1.f - u1) * ex1;
      } else {                 // prec update (hoisted from old pass2)
        const int n = tid - 384;   // 0..127
        float wws = sm[P2_SCAL + S_WWSUM];
        sm[P2_PREC + n] = (1.f - wws) * sm[P2_PREC + n] + sm[P2_WW + n];
      }
      __syncthreads();
      // ---- phase 7: out projection (no trailing barrier needed)
      {
        const int o = tid >> 3, seg = tid & 7;
        const float4* wrow = (const float4*)(W_out + (size_t)o * 576) + seg * 18;
        const float4* hb = (const float4*)(sm + P2_H) + seg * 18;
        float p = 0.f;
#pragma unroll
        for (int q = 0; q < 18; ++q) {
          float4 w = wrow[q]; float4 h = hb[q];
          p += w.x * h.x + w.y * h.y + w.z * h.z + w.w * h.w;
        }
        p += __shfl_down(p, 4, 8);
        p += __shfl_down(p, 2, 8);
        p += __shfl_down(p, 1, 8);
        if (seg == 0) out[((size_t)b * Tt + t) * Oo + o] = p + b_out[o];
      }
    }
  }
}

extern "C" void kernel_launch(void* const* d_in, const int* in_sizes, int n_in,
                              void* d_out, int out_size, void* d_ws, size_t ws_size,
                              hipStream_t stream) {
  (void)in_sizes; (void)n_in; (void)d_ws; (void)ws_size; (void)out_size;
  const float* x    = (const float*)d_in[0];
  const float* W_ih = (const float*)d_in[1];
  const float* W_hh = (const float*)d_in[2];
  const float* b_ih = (const float*)d_in[3];
  const float* b_hh = (const float*)d_in[4];
  const float* W_if = (const float*)d_in[5];
  const float* b_if = (const float*)d_in[6];
  const float* W_out = (const float*)d_in[7];
  const float* b_out = (const float*)d_in[8];
  float* out = (float*)d_out;

  dnc_init<<<320, TIN, 0, stream>>>(W_ih, W_hh, b_ih, b_hh);

  hipFuncSetAttribute((const void*)dnc_main,
                      hipFuncAttributeMaxDynamicSharedMemorySize, SMEM_BYTES);

  void* args[] = {(void*)&x, (void*)&W_if, (void*)&b_if,
                  (void*)&W_out, (void*)&b_out, (void*)&out};
  hipLaunchCooperativeKernel((void*)dnc_main, dim3(NWG), dim3(NT), args,
                             SMEM_BYTES, stream);
}